// Round 4
// baseline (439.931 us; speedup 1.0000x reference)
//
#include <hip/hip_runtime.h>

typedef __bf16 bf16;
typedef __bf16 bf16x4 __attribute__((ext_vector_type(4)));
typedef __bf16 bf16x8 __attribute__((ext_vector_type(8)));
typedef float f32x4 __attribute__((ext_vector_type(4)));

#define B_ 2
#define S_ 2048
#define D_ 2048
#define H_ 16
#define DH_ 128
#define QKVN 6144

__device__ __forceinline__ void async_load16(const bf16* g, bf16* l) {
    __builtin_amdgcn_global_load_lds((const __attribute__((address_space(1))) void*)g,
                                     (__attribute__((address_space(3))) void*)l, 16, 0, 0);
}

__device__ __forceinline__ unsigned int bf16_bits(float x) {
    bf16 h = (bf16)x;
    return (unsigned int)__builtin_bit_cast(unsigned short, h);
}

// ---------------- x cast: f32 -> bf16, 8 elems/thread -----------------------------
__global__ __launch_bounds__(256) void cvt_kernel(const float* __restrict__ src,
                                                  bf16* __restrict__ dst) {
    size_t i = (size_t)blockIdx.x * 256 + threadIdx.x;
    const float4* s = (const float4*)src;
    float4 a = s[2 * i], b = s[2 * i + 1];
    bf16x8 o;
    o[0] = (bf16)a.x; o[1] = (bf16)a.y; o[2] = (bf16)a.z; o[3] = (bf16)a.w;
    o[4] = (bf16)b.x; o[5] = (bf16)b.y; o[6] = (bf16)b.z; o[7] = (bf16)b.w;
    *(bf16x8*)(dst + 8 * i) = o;
}

// ------- weight transpose + cast: W[K][N] f32 -> Wt[N][K] bf16, 4 matrices --------
__global__ __launch_bounds__(256) void wtrans_kernel(const float* __restrict__ Wq,
                                                     const float* __restrict__ Wk,
                                                     const float* __restrict__ Wv,
                                                     const float* __restrict__ Wo,
                                                     bf16* __restrict__ WqkvT,
                                                     bf16* __restrict__ WoT) {
    __shared__ unsigned int tile[64][65];  // bf16 bits in low half
    int z = blockIdx.z;
    const float* src = (z == 0) ? Wq : (z == 1) ? Wk : (z == 2) ? Wv : Wo;
    bf16* dst = (z < 3) ? (WqkvT + (size_t)z * D_ * D_) : WoT;
    int r0 = blockIdx.y * 64, c0 = blockIdx.x * 64;
    int t = threadIdx.x;
    int tr = t >> 4, tc4 = (t & 15) * 4;
#pragma unroll
    for (int it = 0; it < 4; ++it) {
        int r = it * 16 + tr;
        float4 v = *(const float4*)(src + (size_t)(r0 + r) * D_ + c0 + tc4);
        tile[r][tc4 + 0] = bf16_bits(v.x);
        tile[r][tc4 + 1] = bf16_bits(v.y);
        tile[r][tc4 + 2] = bf16_bits(v.z);
        tile[r][tc4 + 3] = bf16_bits(v.w);
    }
    __syncthreads();
#pragma unroll
    for (int it = 0; it < 4; ++it) {
        int a = it * 16 + tr;
        unsigned u0 = tile[tc4 + 0][a], u1 = tile[tc4 + 1][a];
        unsigned u2 = tile[tc4 + 2][a], u3 = tile[tc4 + 3][a];
        uint2 v;
        v.x = (u0 & 0xffffu) | (u1 << 16);
        v.y = (u2 & 0xffffu) | (u3 << 16);
        *(uint2*)(dst + (size_t)(c0 + a) * D_ + r0 + tc4) = v;
    }
}

// ---------------- V transpose: qkv[:,4096+h*128+dh] -> vt[bh][dh][s], bf16 --------
__global__ __launch_bounds__(256) void vtrans_kernel(const bf16* __restrict__ qkv,
                                                     bf16* __restrict__ vt) {
    __shared__ unsigned int tile[64][65];
    int bh = blockIdx.z;
    int b = bh >> 4, h = bh & 15;
    int s0 = blockIdx.x * 64, d0 = blockIdx.y * 64;
    int t = threadIdx.x, tr = t >> 4, tc4 = (t & 15) * 4;
#pragma unroll
    for (int it = 0; it < 4; ++it) {
        int r = it * 16 + tr;  // s offset
        uint2 v = *(const uint2*)(qkv + (size_t)(b * S_ + s0 + r) * QKVN + 2 * D_ + h * DH_ + d0 + tc4);
        tile[r][tc4 + 0] = v.x & 0xffffu;
        tile[r][tc4 + 1] = v.x >> 16;
        tile[r][tc4 + 2] = v.y & 0xffffu;
        tile[r][tc4 + 3] = v.y >> 16;
    }
    __syncthreads();
#pragma unroll
    for (int it = 0; it < 4; ++it) {
        int a = it * 16 + tr;  // dh offset
        unsigned u0 = tile[tc4 + 0][a], u1 = tile[tc4 + 1][a];
        unsigned u2 = tile[tc4 + 2][a], u3 = tile[tc4 + 3][a];
        uint2 v;
        v.x = (u0 & 0xffffu) | (u1 << 16);
        v.y = (u2 & 0xffffu) | (u3 << 16);
        *(uint2*)(vt + (size_t)bh * DH_ * S_ + (size_t)(d0 + a) * S_ + s0 + tc4) = v;
    }
}

// ---------------- m97-style GEMM: C[M][N] = A[M][K] @ Bt[N][K]^T ------------------
template <typename CT>
__global__ __launch_bounds__(256) void gemm_bt(const bf16* __restrict__ A,
                                               const bf16* __restrict__ Bt,
                                               CT* __restrict__ C,
                                               int M, int N, int K) {
    __shared__ __align__(16) bf16 As[128 * 32];
    __shared__ __align__(16) bf16 Bs[128 * 32];
    int t = threadIdx.x;
    int w = t >> 6, l = t & 63;
    int quad = l >> 4, lr = l & 15;
    int wr = w >> 1, wc = w & 1;
    size_t m0 = (size_t)blockIdx.y * 128, n0 = (size_t)blockIdx.x * 128;
    int srow = l >> 2, scol = (l & 3) * 8;

    f32x4 acc[4][4];
#pragma unroll
    for (int i = 0; i < 4; ++i)
#pragma unroll
        for (int j = 0; j < 4; ++j) acc[i][j] = (f32x4){0.f, 0.f, 0.f, 0.f};

    for (int k0 = 0; k0 < K; k0 += 32) {
        __syncthreads();
#pragma unroll
        for (int i = 0; i < 2; ++i) {
            int c = w * 2 + i;
            async_load16(A + (m0 + c * 16 + srow) * (size_t)K + k0 + scol, As + c * 512);
            async_load16(Bt + (n0 + c * 16 + srow) * (size_t)K + k0 + scol, Bs + c * 512);
        }
        asm volatile("s_waitcnt vmcnt(0)" ::: "memory");
        __syncthreads();
        bf16x8 af[4], bfr[4];
#pragma unroll
        for (int i = 0; i < 4; ++i) af[i] = *(const bf16x8*)(As + (wr * 64 + i * 16 + lr) * 32 + quad * 8);
#pragma unroll
        for (int j = 0; j < 4; ++j) bfr[j] = *(const bf16x8*)(Bs + (wc * 64 + j * 16 + lr) * 32 + quad * 8);
#pragma unroll
        for (int i = 0; i < 4; ++i)
#pragma unroll
            for (int j = 0; j < 4; ++j)
                acc[i][j] = __builtin_amdgcn_mfma_f32_16x16x32_bf16(af[i], bfr[j], acc[i][j], 0, 0, 0);
    }

    size_t bm = m0 + wr * 64 + quad * 4;
    size_t bn = n0 + wc * 64 + lr;
#pragma unroll
    for (int i = 0; i < 4; ++i)
#pragma unroll
        for (int j = 0; j < 4; ++j)
#pragma unroll
            for (int r = 0; r < 4; ++r)
                C[(bm + i * 16 + r) * (size_t)N + bn + j * 16] = (CT)acc[i][j][r];
}

// ========== 256x256 8-phase GEMM for QKV: C[4096][6144] = A[4096][2048] @ Bt^T ====
// Swizzle: Guideline-4 chunk-XOR, physical chunk (row,c) holds logical
// (row, c^(row&7)); staging source inverse-permuted (verified r3: conflicts=0).
// Round-4 change: DEEP PREFETCH. Buffer nb (tile kt-1) is fully dead once tile
// kt starts, so ALL FOUR half-tiles of kt+1 are issued at kt's phase 0
// (order A0,B0,B1,A1), with late staggered waits:
//   end-ph0 vmcnt(10) -> B1(kt) resident   (cover 4 phases)
//   end-ph1 vmcnt(8)  -> A1(kt) resident   (cover 5 phases)
//   end-ph3 vmcnt(4)  -> A0,B0(kt+1) ready (cover 3 phases)
// vs round-3's 2-phase covers that forced a ~450cy/phase stall equilibrium.
#define QK_K 2048
#define QK_N 6144

__device__ __forceinline__ bf16x8 lds_frag(const bf16* tile, int row, int colByte) {
    int off = row * 128 + (colByte ^ ((row & 7) << 4));
    return *(const bf16x8*)((const char*)tile + off);
}

template <int MH, int NH>
__device__ __forceinline__ void mmaq8(f32x4 (&acc)[8][4], const bf16x8 (&afr)[4][2],
                                      const bf16x8 (&bf)[2][2]) {
    __builtin_amdgcn_s_setprio(1);
#pragma unroll
    for (int i = 0; i < 4; ++i)
#pragma unroll
        for (int j = 0; j < 2; ++j)
#pragma unroll
            for (int kk = 0; kk < 2; ++kk)
                acc[MH * 4 + i][NH * 2 + j] = __builtin_amdgcn_mfma_f32_16x16x32_bf16(
                    afr[i][kk], bf[j][kk], acc[MH * 4 + i][NH * 2 + j], 0, 0, 0);
    __builtin_amdgcn_s_setprio(0);
}

__global__ __launch_bounds__(512, 2) void gemm_qkv(const bf16* __restrict__ A,
                                                   const bf16* __restrict__ Bt,
                                                   bf16* __restrict__ C) {
    __shared__ __align__(16) bf16 As[2][256 * 64];
    __shared__ __align__(16) bf16 Bs[2][256 * 64];

    int t = threadIdx.x;
    int wid = t >> 6, lane = t & 63;
    int quad = lane >> 4, lr = lane & 15;
    int wr = wid >> 2, wn = wid & 3;  // 2 x 4 wave grid

    // XCD swizzle: 384 wgs, 8 XCDs x 48. Column-major: each XCD owns 3 disjoint
    // B-panels; A panels stream (L3-resident).
    int bid = blockIdx.x;
    int swz = (bid & 7) * 48 + (bid >> 3);
    int tn = swz >> 4, tm = swz & 15;
    size_t m0 = (size_t)tm * 256, n0 = (size_t)tn * 256;

    // staging geometry: chunk idx = r*512 + t; row = idx>>3, col-chunk = idx&7;
    // source col-chunk permuted by row&7 (inverse of the read-side XOR).
    int row_r[2], c8s_r[2];
#pragma unroll
    for (int r = 0; r < 2; ++r) {
        int idx = r * 512 + t;
        row_r[r] = idx >> 3;
        c8s_r[r] = (idx & 7) ^ (row_r[r] & 7);
    }

    auto stA = [&](int kt, int bufi, int h) {
#pragma unroll
        for (int r = 0; r < 2; ++r)
            async_load16(A + (m0 + h * 128 + row_r[r]) * (size_t)QK_K + kt * 64 + c8s_r[r] * 8,
                         &As[bufi][(h * 1024 + r * 512 + wid * 64) * 8]);
    };
    auto stB = [&](int kt, int bufi, int h) {
#pragma unroll
        for (int r = 0; r < 2; ++r)
            async_load16(Bt + (n0 + h * 128 + row_r[r]) * (size_t)QK_K + kt * 64 + c8s_r[r] * 8,
                         &Bs[bufi][(h * 1024 + r * 512 + wid * 64) * 8]);
    };

    f32x4 acc[8][4];
#pragma unroll
    for (int i = 0; i < 8; ++i)
#pragma unroll
        for (int j = 0; j < 4; ++j) acc[i][j] = (f32x4){0.f, 0.f, 0.f, 0.f};

    bf16x8 afr[4][2], bf0[2][2], bf1[2][2];

    auto readA = [&](int bufi, int mh) {
#pragma unroll
        for (int i = 0; i < 4; ++i)
#pragma unroll
            for (int kk = 0; kk < 2; ++kk)
                afr[i][kk] = lds_frag(As[bufi], mh * 128 + wr * 64 + i * 16 + lr, kk * 64 + quad * 16);
    };
    auto readB = [&](int bufi, int nh, bf16x8 (&bf)[2][2]) {
#pragma unroll
        for (int j = 0; j < 2; ++j)
#pragma unroll
            for (int kk = 0; kk < 2; ++kk)
                bf[j][kk] = lds_frag(Bs[bufi], nh * 128 + wn * 32 + j * 16 + lr, kk * 64 + quad * 16);
    };

    // prologue: stage tile 0 (A0,B0,B1,A1); wait for A0,B0
    stA(0, 0, 0);
    stB(0, 0, 0);
    stB(0, 0, 1);
    stA(0, 0, 1);
    asm volatile("s_waitcnt vmcnt(4)" ::: "memory");
    __builtin_amdgcn_s_barrier();

    const int NKT = QK_K / 64;  // 32
    for (int kt = 0; kt < NKT - 1; ++kt) {
        int cb = kt & 1, nb = cb ^ 1;
        // ---- phase 0: stage ALL of tile kt+1; quadrant (0,0) ----
        stA(kt + 1, nb, 0);
        stB(kt + 1, nb, 0);
        stB(kt + 1, nb, 1);
        stA(kt + 1, nb, 1);
        readA(cb, 0);
        readB(cb, 0, bf0);
        __builtin_amdgcn_s_barrier();
        asm volatile("s_waitcnt lgkmcnt(0)" ::: "memory");
        __builtin_amdgcn_sched_barrier(0);
        mmaq8<0, 0>(acc, afr, bf0);
        asm volatile("s_waitcnt vmcnt(10)" ::: "memory");  // B1(kt) resident
        __builtin_amdgcn_s_barrier();
        // ---- phase 1: quadrant (0,1) ----
        readB(cb, 1, bf1);
        __builtin_amdgcn_s_barrier();
        asm volatile("s_waitcnt lgkmcnt(0)" ::: "memory");
        __builtin_amdgcn_sched_barrier(0);
        mmaq8<0, 1>(acc, afr, bf1);
        asm volatile("s_waitcnt vmcnt(8)" ::: "memory");  // A1(kt) resident
        __builtin_amdgcn_s_barrier();
        // ---- phase 2: quadrant (1,0) ----
        readA(cb, 1);
        __builtin_amdgcn_s_barrier();
        asm volatile("s_waitcnt lgkmcnt(0)" ::: "memory");
        __builtin_amdgcn_sched_barrier(0);
        mmaq8<1, 0>(acc, afr, bf0);
        __builtin_amdgcn_s_barrier();
        // ---- phase 3: quadrant (1,1); wait A0,B0 of kt+1 ----
        mmaq8<1, 1>(acc, afr, bf1);
        asm volatile("s_waitcnt vmcnt(4)" ::: "memory");  // A0,B0(kt+1) resident
        __builtin_amdgcn_s_barrier();
    }

    {  // peeled last tile (no staging; entry outstanding = B1,A1 of this tile)
        int cb = (NKT - 1) & 1;
        readA(cb, 0);
        readB(cb, 0, bf0);
        __builtin_amdgcn_s_barrier();
        asm volatile("s_waitcnt lgkmcnt(0)" ::: "memory");
        __builtin_amdgcn_sched_barrier(0);
        mmaq8<0, 0>(acc, afr, bf0);
        asm volatile("s_waitcnt vmcnt(2)" ::: "memory");  // B1 resident
        __builtin_amdgcn_s_barrier();
        readB(cb, 1, bf1);
        __builtin_amdgcn_s_barrier();
        asm volatile("s_waitcnt lgkmcnt(0)" ::: "memory");
        __builtin_amdgcn_sched_barrier(0);
        mmaq8<0, 1>(acc, afr, bf1);
        asm volatile("s_waitcnt vmcnt(0)" ::: "memory");  // A1 resident
        __builtin_amdgcn_s_barrier();
        readA(cb, 1);
        asm volatile("s_waitcnt lgkmcnt(0)" ::: "memory");
        __builtin_amdgcn_sched_barrier(0);
        mmaq8<1, 0>(acc, afr, bf0);
        mmaq8<1, 1>(acc, afr, bf1);
    }

    // epilogue: C/D layout col=lr, row=quad*4+r per 16x16 frag
#pragma unroll
    for (int mh = 0; mh < 2; ++mh)
#pragma unroll
        for (int i = 0; i < 4; ++i)
#pragma unroll
            for (int nh = 0; nh < 2; ++nh)
#pragma unroll
                for (int j = 0; j < 2; ++j)
#pragma unroll
                    for (int r = 0; r < 4; ++r) {
                        size_t row = m0 + mh * 128 + wr * 64 + i * 16 + quad * 4 + r;
                        size_t col = n0 + nh * 128 + wn * 32 + j * 16 + lr;
                        C[row * QK_N + col] = (bf16)acc[mh * 4 + i][nh * 2 + j][r];
                    }
}

// ---------------- flash attention, causal ----------------------------------------
__global__ __launch_bounds__(128) void attn_kernel(const bf16* __restrict__ qkv,
                                                   const bf16* __restrict__ vt,
                                                   bf16* __restrict__ ctx) {
    __shared__ __align__(16) bf16 Ks[2][64 * 128];    // [key][16B-chunk c ^ (key&7)]
    __shared__ __align__(16) bf16 Vts[2][128 * 64];   // [dh][16B-chunk c ^ (dh&7)]
    __shared__ __align__(16) bf16 Ps[2][32][68];      // per-wave P round-trip

    int y = blockIdx.y;
    int p = blockIdx.x;
    int b = y >> 4, h = y & 15;
    int t = threadIdx.x, w = t >> 6, l = t & 63;
    int quad = l >> 4, lr = l & 15;

    const bf16* qbase = qkv + (size_t)b * S_ * QKVN + h * DH_;
    const bf16* kbase = qbase + D_;
    const bf16* vbase = vt + (size_t)y * DH_ * S_;

    const int qtA = p, qtB = 31 - p;
    const int nA = p + 1;  // iters for tile A; total 33

    auto stage = [&](int kt, int bi) {
#pragma unroll
        for (int ii = 0; ii < 8; ++ii) {
            int i = 8 * w + ii;
            int row = 4 * i + (l >> 4);
            int cl = (l & 15) ^ (row & 7);
            async_load16(kbase + (size_t)(kt * 64 + row) * QKVN + cl * 8, Ks[bi] + i * 512);
        }
#pragma unroll
        for (int ii = 0; ii < 8; ++ii) {
            int i = 8 * w + ii;
            int dh = 8 * i + (l >> 3);
            int cl = (l & 7) ^ (dh & 7);
            async_load16(vbase + (size_t)dh * S_ + kt * 64 + cl * 8, Vts[bi] + i * 512);
        }
    };

    const float sc2 = 0.12751745f;  // (1/sqrt(128)) * log2(e), folded into Q

    int qt = qtA, q0 = qt * 64;
    bf16x8 qf[2][4];
    auto loadQ = [&]() {
#pragma unroll
        for (int g = 0; g < 2; ++g)
#pragma unroll
            for (int kk = 0; kk < 4; ++kk) {
                bf16x8 raw = *(const bf16x8*)(qbase + (size_t)(q0 + w * 32 + g * 16 + lr) * QKVN + kk * 32 + quad * 8);
#pragma unroll
                for (int e = 0; e < 8; ++e) qf[g][kk][e] = (bf16)((float)raw[e] * sc2);
            }
    };
    loadQ();

    float L_r[2][4];
    f32x4 o[2][8];
#pragma unroll
    for (int g = 0; g < 2; ++g) {
#pragma unroll
        for (int r = 0; r < 4; ++r) L_r[g][r] = 0.f;
#pragma unroll
        for (int nt = 0; nt < 8; ++nt) o[g][nt] = (f32x4){0.f, 0.f, 0.f, 0.f};
    }

    auto epilogue = [&](int q0e) {
#pragma unroll
        for (int g = 0; g < 2; ++g) {
#pragma unroll
            for (int d = 1; d < 16; d <<= 1)
#pragma unroll
                for (int r = 0; r < 4; ++r) L_r[g][r] += __shfl_xor(L_r[g][r], d, 64);
#pragma unroll
            for (int r = 0; r < 4; ++r) {
                float inv = __builtin_amdgcn_rcpf(L_r[g][r]);
                int q = q0e + w * 32 + g * 16 + quad * 4 + r;
#pragma unroll
                for (int nt = 0; nt < 8; ++nt)
                    ctx[(size_t)(b * S_ + q) * D_ + h * DH_ + nt * 16 + lr] = (bf16)(o[g][nt][r] * inv);
            }
        }
    };

    stage(0, 0);  // prologue

    for (int it = 0; it < 33; ++it) {
        int buf = it & 1;
        asm volatile("s_waitcnt vmcnt(0)" ::: "memory");
        __syncthreads();
        if (it + 1 < 33) {
            int nit = it + 1;
            int nkt = (nit < nA) ? nit : (nit - nA);
            stage(nkt, buf ^ 1);  // in flight across this iter's compute
        }
        int kt = (it < nA) ? it : (it - nA);

        // S = Q K^T: 2 row-groups x 64 keys; each kf feeds 2 MFMAs
        f32x4 s[2][4];
#pragma unroll
        for (int g = 0; g < 2; ++g)
#pragma unroll
            for (int jt = 0; jt < 4; ++jt) s[g][jt] = (f32x4){0.f, 0.f, 0.f, 0.f};
#pragma unroll
        for (int kk = 0; kk < 4; ++kk)
#pragma unroll
            for (int jt = 0; jt < 4; ++jt) {
                bf16x8 kf = *(const bf16x8*)(Ks[buf] + (jt * 16 + lr) * 128 + ((4 * kk + quad) ^ (lr & 7)) * 8);
                s[0][jt] = __builtin_amdgcn_mfma_f32_16x16x32_bf16(qf[0][kk], kf, s[0][jt], 0, 0, 0);
                s[1][jt] = __builtin_amdgcn_mfma_f32_16x16x32_bf16(qf[1][kk], kf, s[1][jt], 0, 0, 0);
            }

        // exp2 (m=0) + mask (diag k-tile only) + per-lane L accumulation + P store
        bool diag = (kt == qt);
#pragma unroll
        for (int g = 0; g < 2; ++g) {
#pragma unroll
            for (int jt = 0; jt < 4; ++jt) {
                int keyi = jt * 16 + lr;
#pragma unroll
                for (int r = 0; r < 4; ++r) {
                    float s2 = s[g][jt][r];
                    if (diag && keyi > w * 32 + g * 16 + quad * 4 + r) s2 = -3.0e38f;
                    float pv = __builtin_amdgcn_exp2f(s2);
                    s[g][jt][r] = pv;
                    L_r[g][r] += pv;
                }
            }
#pragma unroll
            for (int jt = 0; jt < 4; ++jt)
#pragma unroll
                for (int r = 0; r < 4; ++r)
                    Ps[w][g * 16 + quad * 4 + r][jt * 16 + lr] = (bf16)s[g][jt][r];
        }
        asm volatile("s_waitcnt lgkmcnt(0)" ::: "memory");  // per-wave Ps region

        // O += P @ V: each vf feeds 2 MFMAs
#pragma unroll
        for (int ks = 0; ks < 2; ++ks) {
            bf16x8 pf[2];
#pragma unroll
            for (int g = 0; g < 2; ++g) {
                const bf16* pp = &Ps[w][g * 16 + lr][ks * 32 + quad * 8];
                bf16x4 lo = *(const bf16x4*)pp;
                bf16x4 hi = *(const bf16x4*)(pp + 4);
                pf[g] = __builtin_shufflevector(lo, hi, 0, 1, 2, 3, 4, 5, 6, 7);
            }
#pragma unroll
            for (int nt = 0; nt < 8; ++nt) {
                bf16x8 vf = *(const bf16x8*)(Vts[buf] + (nt * 16 + lr) * 64 + ((4 * ks + quad) ^ (lr & 7)) * 8);
                o[0][nt] = __builtin_amdgcn_mfma_f32_16x16x32_bf16(pf[0], vf, o[0][nt], 0, 0, 0);
                o[1][nt] = __builtin_amdgcn_mfma_f32_16x16x32_bf16(pf[1], vf, o[1][nt], 0, 0, 0);
            }
        }

        // tile switch A -> B after A's diagonal iteration
        if (it == nA - 1) {
            epilogue(q0);
            qt = qtB;
            q0 = qt * 64;
            loadQ();
#pragma unroll
            for (int g = 0; g < 2; ++g) {
#pragma unroll
                for (int r = 0; r < 4; ++r) L_r[g][r] = 0.f;
#pragma unroll
                for (int nt = 0; nt < 8; ++nt) o[g][nt] = (f32x4){0.f, 0.f, 0.f, 0.f};
            }
        }
    }

    epilogue(q0);  // tile B
}

extern "C" void kernel_launch(void* const* d_in, const int* in_sizes, int n_in,
                              void* d_out, int out_size, void* d_ws, size_t ws_size,
                              hipStream_t stream) {
    const float* x  = (const float*)d_in[0];
    const float* Wq = (const float*)d_in[1];
    const float* Wk = (const float*)d_in[2];
    const float* Wv = (const float*)d_in[3];
    const float* Wo = (const float*)d_in[4];
    float* out = (float*)d_out;

    char* ws = (char*)d_ws;
    bf16* WqkvT = (bf16*)(ws);                       // 3*2048*2048*2 = 25165824
    bf16* WoT   = (bf16*)(ws + 25165824);            // 2048*2048*2   =  8388608
    bf16* qkv   = (bf16*)(ws + 33554432);            // 4096*6144*2   = 50331648
    bf16* vt    = (bf16*)(ws + 83886080);            // 32*128*2048*2 = 16777216
    bf16* ctx   = (bf16*)(ws + 100663296);           // 4096*2048*2   = 16777216
    bf16* xb    = (bf16*)(ws + 117440512);           // 4096*2048*2   = 16777216
    // total ws use: 134217728 bytes (128 MiB)

    cvt_kernel<<<4096, 256, 0, stream>>>(x, xb);
    wtrans_kernel<<<dim3(32, 32, 4), 256, 0, stream>>>(Wq, Wk, Wv, Wo, WqkvT, WoT);
    gemm_qkv<<<dim3(384), 512, 0, stream>>>(xb, WqkvT, qkv);
    vtrans_kernel<<<dim3(32, 2, 32), 256, 0, stream>>>(qkv, vt);
    attn_kernel<<<dim3(16, 32), 128, 0, stream>>>(qkv, vt, ctx);
    gemm_bt<float><<<dim3(16, 32), 256, 0, stream>>>(ctx, WoT, out, B_ * S_, D_, D_);
}

// Round 5
// 411.764 us; speedup vs baseline: 1.0684x; 1.0684x over previous
//
#include <hip/hip_runtime.h>

typedef __bf16 bf16;
typedef __bf16 bf16x4 __attribute__((ext_vector_type(4)));
typedef __bf16 bf16x8 __attribute__((ext_vector_type(8)));
typedef float f32x4 __attribute__((ext_vector_type(4)));

#define B_ 2
#define S_ 2048
#define D_ 2048
#define H_ 16
#define DH_ 128
#define QKVN 6144

__device__ __forceinline__ void async_load16(const bf16* g, bf16* l) {
    __builtin_amdgcn_global_load_lds((const __attribute__((address_space(1))) void*)g,
                                     (__attribute__((address_space(3))) void*)l, 16, 0, 0);
}

__device__ __forceinline__ unsigned int bf16_bits(float x) {
    bf16 h = (bf16)x;
    return (unsigned int)__builtin_bit_cast(unsigned short, h);
}

// ---------------- x cast: f32 -> bf16, 8 elems/thread -----------------------------
__global__ __launch_bounds__(256) void cvt_kernel(const float* __restrict__ src,
                                                  bf16* __restrict__ dst) {
    size_t i = (size_t)blockIdx.x * 256 + threadIdx.x;
    const float4* s = (const float4*)src;
    float4 a = s[2 * i], b = s[2 * i + 1];
    bf16x8 o;
    o[0] = (bf16)a.x; o[1] = (bf16)a.y; o[2] = (bf16)a.z; o[3] = (bf16)a.w;
    o[4] = (bf16)b.x; o[5] = (bf16)b.y; o[6] = (bf16)b.z; o[7] = (bf16)b.w;
    *(bf16x8*)(dst + 8 * i) = o;
}

// ------- weight transpose + cast: W[K][N] f32 -> Wt[N][K] bf16, 4 matrices --------
__global__ __launch_bounds__(256) void wtrans_kernel(const float* __restrict__ Wq,
                                                     const float* __restrict__ Wk,
                                                     const float* __restrict__ Wv,
                                                     const float* __restrict__ Wo,
                                                     bf16* __restrict__ WqkvT,
                                                     bf16* __restrict__ WoT) {
    __shared__ unsigned int tile[64][65];  // bf16 bits in low half
    int z = blockIdx.z;
    const float* src = (z == 0) ? Wq : (z == 1) ? Wk : (z == 2) ? Wv : Wo;
    bf16* dst = (z < 3) ? (WqkvT + (size_t)z * D_ * D_) : WoT;
    int r0 = blockIdx.y * 64, c0 = blockIdx.x * 64;
    int t = threadIdx.x;
    int tr = t >> 4, tc4 = (t & 15) * 4;
#pragma unroll
    for (int it = 0; it < 4; ++it) {
        int r = it * 16 + tr;
        float4 v = *(const float4*)(src + (size_t)(r0 + r) * D_ + c0 + tc4);
        tile[r][tc4 + 0] = bf16_bits(v.x);
        tile[r][tc4 + 1] = bf16_bits(v.y);
        tile[r][tc4 + 2] = bf16_bits(v.z);
        tile[r][tc4 + 3] = bf16_bits(v.w);
    }
    __syncthreads();
#pragma unroll
    for (int it = 0; it < 4; ++it) {
        int a = it * 16 + tr;
        unsigned u0 = tile[tc4 + 0][a], u1 = tile[tc4 + 1][a];
        unsigned u2 = tile[tc4 + 2][a], u3 = tile[tc4 + 3][a];
        uint2 v;
        v.x = (u0 & 0xffffu) | (u1 << 16);
        v.y = (u2 & 0xffffu) | (u3 << 16);
        *(uint2*)(dst + (size_t)(c0 + a) * D_ + r0 + tc4) = v;
    }
}

// ---------------- V transpose: qkv[:,4096+h*128+dh] -> vt[bh][dh][s], bf16 --------
__global__ __launch_bounds__(256) void vtrans_kernel(const bf16* __restrict__ qkv,
                                                     bf16* __restrict__ vt) {
    __shared__ unsigned int tile[64][65];
    int bh = blockIdx.z;
    int b = bh >> 4, h = bh & 15;
    int s0 = blockIdx.x * 64, d0 = blockIdx.y * 64;
    int t = threadIdx.x, tr = t >> 4, tc4 = (t & 15) * 4;
#pragma unroll
    for (int it = 0; it < 4; ++it) {
        int r = it * 16 + tr;  // s offset
        uint2 v = *(const uint2*)(qkv + (size_t)(b * S_ + s0 + r) * QKVN + 2 * D_ + h * DH_ + d0 + tc4);
        tile[r][tc4 + 0] = v.x & 0xffffu;
        tile[r][tc4 + 1] = v.x >> 16;
        tile[r][tc4 + 2] = v.y & 0xffffu;
        tile[r][tc4 + 3] = v.y >> 16;
    }
    __syncthreads();
#pragma unroll
    for (int it = 0; it < 4; ++it) {
        int a = it * 16 + tr;  // dh offset
        unsigned u0 = tile[tc4 + 0][a], u1 = tile[tc4 + 1][a];
        unsigned u2 = tile[tc4 + 2][a], u3 = tile[tc4 + 3][a];
        uint2 v;
        v.x = (u0 & 0xffffu) | (u1 << 16);
        v.y = (u2 & 0xffffu) | (u3 << 16);
        *(uint2*)(vt + (size_t)bh * DH_ * S_ + (size_t)(d0 + a) * S_ + s0 + tc4) = v;
    }
}

// ---------------- m97-style GEMM: C[M][N] = A[M][K] @ Bt[N][K]^T ------------------
template <typename CT>
__global__ __launch_bounds__(256) void gemm_bt(const bf16* __restrict__ A,
                                               const bf16* __restrict__ Bt,
                                               CT* __restrict__ C,
                                               int M, int N, int K) {
    __shared__ __align__(16) bf16 As[128 * 32];
    __shared__ __align__(16) bf16 Bs[128 * 32];
    int t = threadIdx.x;
    int w = t >> 6, l = t & 63;
    int quad = l >> 4, lr = l & 15;
    int wr = w >> 1, wc = w & 1;
    size_t m0 = (size_t)blockIdx.y * 128, n0 = (size_t)blockIdx.x * 128;
    int srow = l >> 2, scol = (l & 3) * 8;

    f32x4 acc[4][4];
#pragma unroll
    for (int i = 0; i < 4; ++i)
#pragma unroll
        for (int j = 0; j < 4; ++j) acc[i][j] = (f32x4){0.f, 0.f, 0.f, 0.f};

    for (int k0 = 0; k0 < K; k0 += 32) {
        __syncthreads();
#pragma unroll
        for (int i = 0; i < 2; ++i) {
            int c = w * 2 + i;
            async_load16(A + (m0 + c * 16 + srow) * (size_t)K + k0 + scol, As + c * 512);
            async_load16(Bt + (n0 + c * 16 + srow) * (size_t)K + k0 + scol, Bs + c * 512);
        }
        asm volatile("s_waitcnt vmcnt(0)" ::: "memory");
        __syncthreads();
        bf16x8 af[4], bfr[4];
#pragma unroll
        for (int i = 0; i < 4; ++i) af[i] = *(const bf16x8*)(As + (wr * 64 + i * 16 + lr) * 32 + quad * 8);
#pragma unroll
        for (int j = 0; j < 4; ++j) bfr[j] = *(const bf16x8*)(Bs + (wc * 64 + j * 16 + lr) * 32 + quad * 8);
#pragma unroll
        for (int i = 0; i < 4; ++i)
#pragma unroll
            for (int j = 0; j < 4; ++j)
                acc[i][j] = __builtin_amdgcn_mfma_f32_16x16x32_bf16(af[i], bfr[j], acc[i][j], 0, 0, 0);
    }

    size_t bm = m0 + wr * 64 + quad * 4;
    size_t bn = n0 + wc * 64 + lr;
#pragma unroll
    for (int i = 0; i < 4; ++i)
#pragma unroll
        for (int j = 0; j < 4; ++j)
#pragma unroll
            for (int r = 0; r < 4; ++r)
                C[(bm + i * 16 + r) * (size_t)N + bn + j * 16] = (CT)acc[i][j][r];
}

// ========== 256x256 8-phase GEMM for QKV: faithful m201-template port ============
// Swizzle: chunk-XOR (row,c)->(row, c^(row&7)), inverse-permuted global source
// (r3-verified: SQ_LDS_BANK_CONFLICT = 0).
// Round-5 schedule = the documented template numbers EXACTLY:
//   - loop iteration covers 2 K-tiles (t even in buf0, t+1 in buf1), 8 phases
//   - ONE half-tile (2 loads/thread) staged per phase, ~2-tile prefetch distance
//   - vmcnt(6) ONLY at phases 3 and 7 (once per K-tile), never 0 in main loop
//   - prologue: 4 halves -> vmcnt(4) -> 3 halves -> vmcnt(6)
//   - invariant at iter top: 6 loads outstanding = A0,B0,B1(t+1); each vmcnt(6)
//     retires exactly the next tile's 8 loads
//   - stage-overwrite safety: every stage lands >=2 barriers after the last
//     ds_read of its LDS slot (ledger in round-5 notes)
#define QK_K 2048
#define QK_N 6144

__device__ __forceinline__ bf16x8 lds_frag(const bf16* tile, int row, int colByte) {
    int off = row * 128 + (colByte ^ ((row & 7) << 4));
    return *(const bf16x8*)((const char*)tile + off);
}

template <int MH, int NH>
__device__ __forceinline__ void mmaq8(f32x4 (&acc)[8][4], const bf16x8 (&afr)[4][2],
                                      const bf16x8 (&bf)[2][2]) {
    __builtin_amdgcn_s_setprio(1);
#pragma unroll
    for (int i = 0; i < 4; ++i)
#pragma unroll
        for (int j = 0; j < 2; ++j)
#pragma unroll
            for (int kk = 0; kk < 2; ++kk)
                acc[MH * 4 + i][NH * 2 + j] = __builtin_amdgcn_mfma_f32_16x16x32_bf16(
                    afr[i][kk], bf[j][kk], acc[MH * 4 + i][NH * 2 + j], 0, 0, 0);
    __builtin_amdgcn_s_setprio(0);
}

__global__ __launch_bounds__(512, 2) void gemm_qkv(const bf16* __restrict__ A,
                                                   const bf16* __restrict__ Bt,
                                                   bf16* __restrict__ C) {
    __shared__ __align__(16) bf16 As[2][256 * 64];
    __shared__ __align__(16) bf16 Bs[2][256 * 64];

    int t = threadIdx.x;
    int wid = t >> 6, lane = t & 63;
    int quad = lane >> 4, lr = lane & 15;
    int wr = wid >> 2, wn = wid & 3;  // 2 x 4 wave grid

    // XCD swizzle: 384 wgs, 8 XCDs x 48 contiguous (3 disjoint B-panels/XCD).
    int bid = blockIdx.x;
    int swz = (bid & 7) * 48 + (bid >> 3);
    int tn = swz >> 4, tm = swz & 15;
    size_t m0 = (size_t)tm * 256, n0 = (size_t)tn * 256;

    // staging geometry: chunk idx = r*512 + t; row = idx>>3, col-chunk = idx&7;
    // source col-chunk permuted by row&7 (inverse of the read-side XOR).
    int row_r[2], c8s_r[2];
#pragma unroll
    for (int r = 0; r < 2; ++r) {
        int idx = r * 512 + t;
        row_r[r] = idx >> 3;
        c8s_r[r] = (idx & 7) ^ (row_r[r] & 7);
    }

    auto stA = [&](int kt, int bufi, int h) {  // one half-tile = 2 loads/thread
#pragma unroll
        for (int r = 0; r < 2; ++r)
            async_load16(A + (m0 + h * 128 + row_r[r]) * (size_t)QK_K + kt * 64 + c8s_r[r] * 8,
                         &As[bufi][(h * 1024 + r * 512 + wid * 64) * 8]);
    };
    auto stB = [&](int kt, int bufi, int h) {
#pragma unroll
        for (int r = 0; r < 2; ++r)
            async_load16(Bt + (n0 + h * 128 + row_r[r]) * (size_t)QK_K + kt * 64 + c8s_r[r] * 8,
                         &Bs[bufi][(h * 1024 + r * 512 + wid * 64) * 8]);
    };

    f32x4 acc[8][4];
#pragma unroll
    for (int i = 0; i < 8; ++i)
#pragma unroll
        for (int j = 0; j < 4; ++j) acc[i][j] = (f32x4){0.f, 0.f, 0.f, 0.f};

    bf16x8 afr[4][2], bf0[2][2], bf1[2][2];

    auto readA = [&](int bufi, int mh) {
#pragma unroll
        for (int i = 0; i < 4; ++i)
#pragma unroll
            for (int kk = 0; kk < 2; ++kk)
                afr[i][kk] = lds_frag(As[bufi], mh * 128 + wr * 64 + i * 16 + lr, kk * 64 + quad * 16);
    };
    auto readB = [&](int bufi, int nh, bf16x8 (&bf)[2][2]) {
#pragma unroll
        for (int j = 0; j < 2; ++j)
#pragma unroll
            for (int kk = 0; kk < 2; ++kk)
                bf[j][kk] = lds_frag(Bs[bufi], nh * 128 + wn * 32 + j * 16 + lr, kk * 64 + quad * 16);
    };

    // prologue (template-exact): tile0 full -> vmcnt(4) -> tile1 A0,B0,B1 -> vmcnt(6)
    stA(0, 0, 0); stB(0, 0, 0); stB(0, 0, 1); stA(0, 0, 1);
    asm volatile("s_waitcnt vmcnt(4)" ::: "memory");  // A0,B0(0) resident
    stA(1, 1, 0); stB(1, 1, 0); stB(1, 1, 1);
    asm volatile("s_waitcnt vmcnt(6)" ::: "memory");  // tile0 fully resident
    __builtin_amdgcn_s_barrier();

    // 15 full iterations cover tiles 0..29 (t = 0,2,...,28); peeled tail: 30,31
    for (int it2 = 0; it2 < 15; ++it2) {
        int tt = 2 * it2;
        // ---- ph0: tile t quad (0,0); stage A1(t+1)->buf1 ----
        readA(0, 0);
        readB(0, 0, bf0);
        stA(tt + 1, 1, 1);
        __builtin_amdgcn_s_barrier();
        asm volatile("s_waitcnt lgkmcnt(0)" ::: "memory");
        __builtin_amdgcn_sched_barrier(0);
        mmaq8<0, 0>(acc, afr, bf0);
        __builtin_amdgcn_s_barrier();
        // ---- ph1: quad (0,1); stage A0(t+2)->buf0 ----
        readB(0, 1, bf1);
        stA(tt + 2, 0, 0);
        __builtin_amdgcn_s_barrier();
        asm volatile("s_waitcnt lgkmcnt(0)" ::: "memory");
        __builtin_amdgcn_sched_barrier(0);
        mmaq8<0, 1>(acc, afr, bf1);
        __builtin_amdgcn_s_barrier();
        // ---- ph2: quad (1,0); stage B0(t+2)->buf0 ----
        readA(0, 1);
        stB(tt + 2, 0, 0);
        __builtin_amdgcn_s_barrier();
        asm volatile("s_waitcnt lgkmcnt(0)" ::: "memory");
        __builtin_amdgcn_sched_barrier(0);
        mmaq8<1, 0>(acc, afr, bf0);
        __builtin_amdgcn_s_barrier();
        // ---- ph3: quad (1,1); stage B1(t+2)->buf0; vmcnt(6) -> tile t+1 resident ----
        stB(tt + 2, 0, 1);
        asm volatile("s_waitcnt vmcnt(6)" ::: "memory");
        __builtin_amdgcn_s_barrier();
        mmaq8<1, 1>(acc, afr, bf1);
        __builtin_amdgcn_s_barrier();
        // ---- ph4: tile t+1 quad (0,0); stage A1(t+2)->buf0 ----
        readA(1, 0);
        readB(1, 0, bf0);
        stA(tt + 2, 0, 1);
        __builtin_amdgcn_s_barrier();
        asm volatile("s_waitcnt lgkmcnt(0)" ::: "memory");
        __builtin_amdgcn_sched_barrier(0);
        mmaq8<0, 0>(acc, afr, bf0);
        __builtin_amdgcn_s_barrier();
        // ---- ph5: quad (0,1); stage A0(t+3)->buf1 ----
        readB(1, 1, bf1);
        stA(tt + 3, 1, 0);
        __builtin_amdgcn_s_barrier();
        asm volatile("s_waitcnt lgkmcnt(0)" ::: "memory");
        __builtin_amdgcn_sched_barrier(0);
        mmaq8<0, 1>(acc, afr, bf1);
        __builtin_amdgcn_s_barrier();
        // ---- ph6: quad (1,0); stage B0(t+3)->buf1 ----
        readA(1, 1);
        stB(tt + 3, 1, 0);
        __builtin_amdgcn_s_barrier();
        asm volatile("s_waitcnt lgkmcnt(0)" ::: "memory");
        __builtin_amdgcn_sched_barrier(0);
        mmaq8<1, 0>(acc, afr, bf0);
        __builtin_amdgcn_s_barrier();
        // ---- ph7: quad (1,1); stage B1(t+3)->buf1; vmcnt(6) -> tile t+2 resident ----
        stB(tt + 3, 1, 1);
        asm volatile("s_waitcnt vmcnt(6)" ::: "memory");
        __builtin_amdgcn_s_barrier();
        mmaq8<1, 1>(acc, afr, bf1);
        __builtin_amdgcn_s_barrier();
    }

    {  // peeled tail: tiles 30 (buf0) and 31 (buf1); drain 8 -> 0
        // entry: tile30 resident, outstanding 6 = A0,B0,B1(31)
        readA(0, 0);
        readB(0, 0, bf0);
        stA(31, 1, 1);  // A1(31), outstanding 8
        __builtin_amdgcn_s_barrier();
        asm volatile("s_waitcnt lgkmcnt(0)" ::: "memory");
        __builtin_amdgcn_sched_barrier(0);
        mmaq8<0, 0>(acc, afr, bf0);
        __builtin_amdgcn_s_barrier();
        readB(0, 1, bf1);
        __builtin_amdgcn_s_barrier();
        asm volatile("s_waitcnt lgkmcnt(0)" ::: "memory");
        __builtin_amdgcn_sched_barrier(0);
        mmaq8<0, 1>(acc, afr, bf1);
        __builtin_amdgcn_s_barrier();
        readA(0, 1);
        __builtin_amdgcn_s_barrier();
        asm volatile("s_waitcnt lgkmcnt(0)" ::: "memory");
        __builtin_amdgcn_sched_barrier(0);
        mmaq8<1, 0>(acc, afr, bf0);
        __builtin_amdgcn_s_barrier();
        asm volatile("s_waitcnt vmcnt(0)" ::: "memory");  // tile31 resident
        __builtin_amdgcn_s_barrier();
        mmaq8<1, 1>(acc, afr, bf1);
        __builtin_amdgcn_s_barrier();
        // tile 31 (buf1), nothing outstanding
        readA(1, 0);
        readB(1, 0, bf0);
        asm volatile("s_waitcnt lgkmcnt(0)" ::: "memory");
        __builtin_amdgcn_sched_barrier(0);
        mmaq8<0, 0>(acc, afr, bf0);
        readB(1, 1, bf1);
        asm volatile("s_waitcnt lgkmcnt(0)" ::: "memory");
        __builtin_amdgcn_sched_barrier(0);
        mmaq8<0, 1>(acc, afr, bf1);
        readA(1, 1);
        asm volatile("s_waitcnt lgkmcnt(0)" ::: "memory");
        __builtin_amdgcn_sched_barrier(0);
        mmaq8<1, 0>(acc, afr, bf0);
        mmaq8<1, 1>(acc, afr, bf1);
    }

    // epilogue: C/D layout col=lr, row=quad*4+r per 16x16 frag
#pragma unroll
    for (int mh = 0; mh < 2; ++mh)
#pragma unroll
        for (int i = 0; i < 4; ++i)
#pragma unroll
            for (int nh = 0; nh < 2; ++nh)
#pragma unroll
                for (int j = 0; j < 2; ++j)
#pragma unroll
                    for (int r = 0; r < 4; ++r) {
                        size_t row = m0 + mh * 128 + wr * 64 + i * 16 + quad * 4 + r;
                        size_t col = n0 + nh * 128 + wn * 32 + j * 16 + lr;
                        C[row * QK_N + col] = (bf16)acc[mh * 4 + i][nh * 2 + j][r];
                    }
}

// ---------------- flash attention, causal ----------------------------------------
__global__ __launch_bounds__(128) void attn_kernel(const bf16* __restrict__ qkv,
                                                   const bf16* __restrict__ vt,
                                                   bf16* __restrict__ ctx) {
    __shared__ __align__(16) bf16 Ks[2][64 * 128];    // [key][16B-chunk c ^ (key&7)]
    __shared__ __align__(16) bf16 Vts[2][128 * 64];   // [dh][16B-chunk c ^ (dh&7)]
    __shared__ __align__(16) bf16 Ps[2][32][68];      // per-wave P round-trip

    int y = blockIdx.y;
    int p = blockIdx.x;
    int b = y >> 4, h = y & 15;
    int t = threadIdx.x, w = t >> 6, l = t & 63;
    int quad = l >> 4, lr = l & 15;

    const bf16* qbase = qkv + (size_t)b * S_ * QKVN + h * DH_;
    const bf16* kbase = qbase + D_;
    const bf16* vbase = vt + (size_t)y * DH_ * S_;

    const int qtA = p, qtB = 31 - p;
    const int nA = p + 1;  // iters for tile A; total 33

    auto stage = [&](int kt, int bi) {
#pragma unroll
        for (int ii = 0; ii < 8; ++ii) {
            int i = 8 * w + ii;
            int row = 4 * i + (l >> 4);
            int cl = (l & 15) ^ (row & 7);
            async_load16(kbase + (size_t)(kt * 64 + row) * QKVN + cl * 8, Ks[bi] + i * 512);
        }
#pragma unroll
        for (int ii = 0; ii < 8; ++ii) {
            int i = 8 * w + ii;
            int dh = 8 * i + (l >> 3);
            int cl = (l & 7) ^ (dh & 7);
            async_load16(vbase + (size_t)dh * S_ + kt * 64 + cl * 8, Vts[bi] + i * 512);
        }
    };

    const float sc2 = 0.12751745f;  // (1/sqrt(128)) * log2(e), folded into Q

    int qt = qtA, q0 = qt * 64;
    bf16x8 qf[2][4];
    auto loadQ = [&]() {
#pragma unroll
        for (int g = 0; g < 2; ++g)
#pragma unroll
            for (int kk = 0; kk < 4; ++kk) {
                bf16x8 raw = *(const bf16x8*)(qbase + (size_t)(q0 + w * 32 + g * 16 + lr) * QKVN + kk * 32 + quad * 8);
#pragma unroll
                for (int e = 0; e < 8; ++e) qf[g][kk][e] = (bf16)((float)raw[e] * sc2);
            }
    };
    loadQ();

    float L_r[2][4];
    f32x4 o[2][8];
#pragma unroll
    for (int g = 0; g < 2; ++g) {
#pragma unroll
        for (int r = 0; r < 4; ++r) L_r[g][r] = 0.f;
#pragma unroll
        for (int nt = 0; nt < 8; ++nt) o[g][nt] = (f32x4){0.f, 0.f, 0.f, 0.f};
    }

    auto epilogue = [&](int q0e) {
#pragma unroll
        for (int g = 0; g < 2; ++g) {
#pragma unroll
            for (int d = 1; d < 16; d <<= 1)
#pragma unroll
                for (int r = 0; r < 4; ++r) L_r[g][r] += __shfl_xor(L_r[g][r], d, 64);
#pragma unroll
            for (int r = 0; r < 4; ++r) {
                float inv = __builtin_amdgcn_rcpf(L_r[g][r]);
                int q = q0e + w * 32 + g * 16 + quad * 4 + r;
#pragma unroll
                for (int nt = 0; nt < 8; ++nt)
                    ctx[(size_t)(b * S_ + q) * D_ + h * DH_ + nt * 16 + lr] = (bf16)(o[g][nt][r] * inv);
            }
        }
    };

    stage(0, 0);  // prologue

    for (int it = 0; it < 33; ++it) {
        int buf = it & 1;
        asm volatile("s_waitcnt vmcnt(0)" ::: "memory");
        __syncthreads();
        if (it + 1 < 33) {
            int nit = it + 1;
            int nkt = (nit < nA) ? nit : (nit - nA);
            stage(nkt, buf ^ 1);  // in flight across this iter's compute
        }
        int kt = (it < nA) ? it : (it - nA);

        // S = Q K^T: 2 row-groups x 64 keys; each kf feeds 2 MFMAs
        f32x4 s[2][4];
#pragma unroll
        for (int g = 0; g < 2; ++g)
#pragma unroll
            for (int jt = 0; jt < 4; ++jt) s[g][jt] = (f32x4){0.f, 0.f, 0.f, 0.f};
#pragma unroll
        for (int kk = 0; kk < 4; ++kk)
#pragma unroll
            for (int jt = 0; jt < 4; ++jt) {
                bf16x8 kf = *(const bf16x8*)(Ks[buf] + (jt * 16 + lr) * 128 + ((4 * kk + quad) ^ (lr & 7)) * 8);
                s[0][jt] = __builtin_amdgcn_mfma_f32_16x16x32_bf16(qf[0][kk], kf, s[0][jt], 0, 0, 0);
                s[1][jt] = __builtin_amdgcn_mfma_f32_16x16x32_bf16(qf[1][kk], kf, s[1][jt], 0, 0, 0);
            }

        // exp2 (m=0) + mask (diag k-tile only) + per-lane L accumulation + P store
        bool diag = (kt == qt);
#pragma unroll
        for (int g = 0; g < 2; ++g) {
#pragma unroll
            for (int jt = 0; jt < 4; ++jt) {
                int keyi = jt * 16 + lr;
#pragma unroll
                for (int r = 0; r < 4; ++r) {
                    float s2 = s[g][jt][r];
                    if (diag && keyi > w * 32 + g * 16 + quad * 4 + r) s2 = -3.0e38f;
                    float pv = __builtin_amdgcn_exp2f(s2);
                    s[g][jt][r] = pv;
                    L_r[g][r] += pv;
                }
            }
#pragma unroll
            for (int jt = 0; jt < 4; ++jt)
#pragma unroll
                for (int r = 0; r < 4; ++r)
                    Ps[w][g * 16 + quad * 4 + r][jt * 16 + lr] = (bf16)s[g][jt][r];
        }
        asm volatile("s_waitcnt lgkmcnt(0)" ::: "memory");  // per-wave Ps region

        // O += P @ V: each vf feeds 2 MFMAs
#pragma unroll
        for (int ks = 0; ks < 2; ++ks) {
            bf16x8 pf[2];
#pragma unroll
            for (int g = 0; g < 2; ++g) {
                const bf16* pp = &Ps[w][g * 16 + lr][ks * 32 + quad * 8];
                bf16x4 lo = *(const bf16x4*)pp;
                bf16x4 hi = *(const bf16x4*)(pp + 4);
                pf[g] = __builtin_shufflevector(lo, hi, 0, 1, 2, 3, 4, 5, 6, 7);
            }
#pragma unroll
            for (int nt = 0; nt < 8; ++nt) {
                bf16x8 vf = *(const bf16x8*)(Vts[buf] + (nt * 16 + lr) * 64 + ((4 * ks + quad) ^ (lr & 7)) * 8);
                o[0][nt] = __builtin_amdgcn_mfma_f32_16x16x32_bf16(pf[0], vf, o[0][nt], 0, 0, 0);
                o[1][nt] = __builtin_amdgcn_mfma_f32_16x16x32_bf16(pf[1], vf, o[1][nt], 0, 0, 0);
            }
        }

        // tile switch A -> B after A's diagonal iteration
        if (it == nA - 1) {
            epilogue(q0);
            qt = qtB;
            q0 = qt * 64;
            loadQ();
#pragma unroll
            for (int g = 0; g < 2; ++g) {
#pragma unroll
                for (int r = 0; r < 4; ++r) L_r[g][r] = 0.f;
#pragma unroll
                for (int nt = 0; nt < 8; ++nt) o[g][nt] = (f32x4){0.f, 0.f, 0.f, 0.f};
            }
        }
    }

    epilogue(q0);  // tile B
}

extern "C" void kernel_launch(void* const* d_in, const int* in_sizes, int n_in,
                              void* d_out, int out_size, void* d_ws, size_t ws_size,
                              hipStream_t stream) {
    const float* x  = (const float*)d_in[0];
    const float* Wq = (const float*)d_in[1];
    const float* Wk = (const float*)d_in[2];
    const float* Wv = (const float*)d_in[3];
    const float* Wo = (const float*)d_in[4];
    float* out = (float*)d_out;

    char* ws = (char*)d_ws;
    bf16* WqkvT = (bf16*)(ws);                       // 3*2048*2048*2 = 25165824
    bf16* WoT   = (bf16*)(ws + 25165824);            // 2048*2048*2   =  8388608
    bf16* qkv   = (bf16*)(ws + 33554432);            // 4096*6144*2   = 50331648
    bf16* vt    = (bf16*)(ws + 83886080);            // 32*128*2048*2 = 16777216
    bf16* ctx   = (bf16*)(ws + 100663296);           // 4096*2048*2   = 16777216
    bf16* xb    = (bf16*)(ws + 117440512);           // 4096*2048*2   = 16777216
    // total ws use: 134217728 bytes (128 MiB)

    cvt_kernel<<<4096, 256, 0, stream>>>(x, xb);
    wtrans_kernel<<<dim3(32, 32, 4), 256, 0, stream>>>(Wq, Wk, Wv, Wo, WqkvT, WoT);
    gemm_qkv<<<dim3(384), 512, 0, stream>>>(xb, WqkvT, qkv);
    vtrans_kernel<<<dim3(32, 2, 32), 256, 0, stream>>>(qkv, vt);
    attn_kernel<<<dim3(16, 32), 128, 0, stream>>>(qkv, vt, ctx);
    gemm_bt<float><<<dim3(16, 32), 256, 0, stream>>>(ctx, WoT, out, B_ * S_, D_, D_);
}

// Round 6
// 401.231 us; speedup vs baseline: 1.0965x; 1.0263x over previous
//
#include <hip/hip_runtime.h>

typedef __bf16 bf16;
typedef __bf16 bf16x4 __attribute__((ext_vector_type(4)));
typedef __bf16 bf16x8 __attribute__((ext_vector_type(8)));
typedef float f32x4 __attribute__((ext_vector_type(4)));

#define B_ 2
#define S_ 2048
#define D_ 2048
#define H_ 16
#define DH_ 128
#define QKVN 6144

__device__ __forceinline__ void async_load16(const bf16* g, bf16* l) {
    __builtin_amdgcn_global_load_lds((const __attribute__((address_space(1))) void*)g,
                                     (__attribute__((address_space(3))) void*)l, 16, 0, 0);
}

__device__ __forceinline__ unsigned int bf16_bits(float x) {
    bf16 h = (bf16)x;
    return (unsigned int)__builtin_bit_cast(unsigned short, h);
}

// ---------------- x cast: f32 -> bf16, 8 elems/thread -----------------------------
__global__ __launch_bounds__(256) void cvt_kernel(const float* __restrict__ src,
                                                  bf16* __restrict__ dst) {
    size_t i = (size_t)blockIdx.x * 256 + threadIdx.x;
    const float4* s = (const float4*)src;
    float4 a = s[2 * i], b = s[2 * i + 1];
    bf16x8 o;
    o[0] = (bf16)a.x; o[1] = (bf16)a.y; o[2] = (bf16)a.z; o[3] = (bf16)a.w;
    o[4] = (bf16)b.x; o[5] = (bf16)b.y; o[6] = (bf16)b.z; o[7] = (bf16)b.w;
    *(bf16x8*)(dst + 8 * i) = o;
}

// ------- weight transpose + cast: W[K][N] f32 -> Wt[N][K] bf16, 4 matrices --------
__global__ __launch_bounds__(256) void wtrans_kernel(const float* __restrict__ Wq,
                                                     const float* __restrict__ Wk,
                                                     const float* __restrict__ Wv,
                                                     const float* __restrict__ Wo,
                                                     bf16* __restrict__ WqkvT,
                                                     bf16* __restrict__ WoT) {
    __shared__ unsigned int tile[64][65];  // bf16 bits in low half
    int z = blockIdx.z;
    const float* src = (z == 0) ? Wq : (z == 1) ? Wk : (z == 2) ? Wv : Wo;
    bf16* dst = (z < 3) ? (WqkvT + (size_t)z * D_ * D_) : WoT;
    int r0 = blockIdx.y * 64, c0 = blockIdx.x * 64;
    int t = threadIdx.x;
    int tr = t >> 4, tc4 = (t & 15) * 4;
#pragma unroll
    for (int it = 0; it < 4; ++it) {
        int r = it * 16 + tr;
        float4 v = *(const float4*)(src + (size_t)(r0 + r) * D_ + c0 + tc4);
        tile[r][tc4 + 0] = bf16_bits(v.x);
        tile[r][tc4 + 1] = bf16_bits(v.y);
        tile[r][tc4 + 2] = bf16_bits(v.z);
        tile[r][tc4 + 3] = bf16_bits(v.w);
    }
    __syncthreads();
#pragma unroll
    for (int it = 0; it < 4; ++it) {
        int a = it * 16 + tr;
        unsigned u0 = tile[tc4 + 0][a], u1 = tile[tc4 + 1][a];
        unsigned u2 = tile[tc4 + 2][a], u3 = tile[tc4 + 3][a];
        uint2 v;
        v.x = (u0 & 0xffffu) | (u1 << 16);
        v.y = (u2 & 0xffffu) | (u3 << 16);
        *(uint2*)(dst + (size_t)(c0 + a) * D_ + r0 + tc4) = v;
    }
}

// ---------------- V transpose: qkv[:,4096+h*128+dh] -> vt[bh][dh][s], bf16 --------
__global__ __launch_bounds__(256) void vtrans_kernel(const bf16* __restrict__ qkv,
                                                     bf16* __restrict__ vt) {
    __shared__ unsigned int tile[64][65];
    int bh = blockIdx.z;
    int b = bh >> 4, h = bh & 15;
    int s0 = blockIdx.x * 64, d0 = blockIdx.y * 64;
    int t = threadIdx.x, tr = t >> 4, tc4 = (t & 15) * 4;
#pragma unroll
    for (int it = 0; it < 4; ++it) {
        int r = it * 16 + tr;  // s offset
        uint2 v = *(const uint2*)(qkv + (size_t)(b * S_ + s0 + r) * QKVN + 2 * D_ + h * DH_ + d0 + tc4);
        tile[r][tc4 + 0] = v.x & 0xffffu;
        tile[r][tc4 + 1] = v.x >> 16;
        tile[r][tc4 + 2] = v.y & 0xffffu;
        tile[r][tc4 + 3] = v.y >> 16;
    }
    __syncthreads();
#pragma unroll
    for (int it = 0; it < 4; ++it) {
        int a = it * 16 + tr;  // dh offset
        unsigned u0 = tile[tc4 + 0][a], u1 = tile[tc4 + 1][a];
        unsigned u2 = tile[tc4 + 2][a], u3 = tile[tc4 + 3][a];
        uint2 v;
        v.x = (u0 & 0xffffu) | (u1 << 16);
        v.y = (u2 & 0xffffu) | (u3 << 16);
        *(uint2*)(vt + (size_t)bh * DH_ * S_ + (size_t)(d0 + a) * S_ + s0 + tc4) = v;
    }
}

// ---------------- m97-style GEMM: C[M][N] = A[M][K] @ Bt[N][K]^T ------------------
template <typename CT>
__global__ __launch_bounds__(256) void gemm_bt(const bf16* __restrict__ A,
                                               const bf16* __restrict__ Bt,
                                               CT* __restrict__ C,
                                               int M, int N, int K) {
    __shared__ __align__(16) bf16 As[128 * 32];
    __shared__ __align__(16) bf16 Bs[128 * 32];
    int t = threadIdx.x;
    int w = t >> 6, l = t & 63;
    int quad = l >> 4, lr = l & 15;
    int wr = w >> 1, wc = w & 1;
    size_t m0 = (size_t)blockIdx.y * 128, n0 = (size_t)blockIdx.x * 128;
    int srow = l >> 2, scol = (l & 3) * 8;

    f32x4 acc[4][4];
#pragma unroll
    for (int i = 0; i < 4; ++i)
#pragma unroll
        for (int j = 0; j < 4; ++j) acc[i][j] = (f32x4){0.f, 0.f, 0.f, 0.f};

    for (int k0 = 0; k0 < K; k0 += 32) {
        __syncthreads();
#pragma unroll
        for (int i = 0; i < 2; ++i) {
            int c = w * 2 + i;
            async_load16(A + (m0 + c * 16 + srow) * (size_t)K + k0 + scol, As + c * 512);
            async_load16(Bt + (n0 + c * 16 + srow) * (size_t)K + k0 + scol, Bs + c * 512);
        }
        asm volatile("s_waitcnt vmcnt(0)" ::: "memory");
        __syncthreads();
        bf16x8 af[4], bfr[4];
#pragma unroll
        for (int i = 0; i < 4; ++i) af[i] = *(const bf16x8*)(As + (wr * 64 + i * 16 + lr) * 32 + quad * 8);
#pragma unroll
        for (int j = 0; j < 4; ++j) bfr[j] = *(const bf16x8*)(Bs + (wc * 64 + j * 16 + lr) * 32 + quad * 8);
#pragma unroll
        for (int i = 0; i < 4; ++i)
#pragma unroll
            for (int j = 0; j < 4; ++j)
                acc[i][j] = __builtin_amdgcn_mfma_f32_16x16x32_bf16(af[i], bfr[j], acc[i][j], 0, 0, 0);
    }

    size_t bm = m0 + wr * 64 + quad * 4;
    size_t bn = n0 + wc * 64 + lr;
#pragma unroll
    for (int i = 0; i < 4; ++i)
#pragma unroll
        for (int j = 0; j < 4; ++j)
#pragma unroll
            for (int r = 0; r < 4; ++r)
                C[(bm + i * 16 + r) * (size_t)N + bn + j * 16] = (CT)acc[i][j][r];
}

// ========== 256x256 8-phase GEMM for QKV (r5 schedule, FROZEN) ====================
#define QK_K 2048
#define QK_N 6144

__device__ __forceinline__ bf16x8 lds_frag(const bf16* tile, int row, int colByte) {
    int off = row * 128 + (colByte ^ ((row & 7) << 4));
    return *(const bf16x8*)((const char*)tile + off);
}

template <int MH, int NH>
__device__ __forceinline__ void mmaq8(f32x4 (&acc)[8][4], const bf16x8 (&afr)[4][2],
                                      const bf16x8 (&bf)[2][2]) {
    __builtin_amdgcn_s_setprio(1);
#pragma unroll
    for (int i = 0; i < 4; ++i)
#pragma unroll
        for (int j = 0; j < 2; ++j)
#pragma unroll
            for (int kk = 0; kk < 2; ++kk)
                acc[MH * 4 + i][NH * 2 + j] = __builtin_amdgcn_mfma_f32_16x16x32_bf16(
                    afr[i][kk], bf[j][kk], acc[MH * 4 + i][NH * 2 + j], 0, 0, 0);
    __builtin_amdgcn_s_setprio(0);
}

__global__ __launch_bounds__(512, 2) void gemm_qkv(const bf16* __restrict__ A,
                                                   const bf16* __restrict__ Bt,
                                                   bf16* __restrict__ C) {
    __shared__ __align__(16) bf16 As[2][256 * 64];
    __shared__ __align__(16) bf16 Bs[2][256 * 64];

    int t = threadIdx.x;
    int wid = t >> 6, lane = t & 63;
    int quad = lane >> 4, lr = lane & 15;
    int wr = wid >> 2, wn = wid & 3;  // 2 x 4 wave grid

    int bid = blockIdx.x;
    int swz = (bid & 7) * 48 + (bid >> 3);
    int tn = swz >> 4, tm = swz & 15;
    size_t m0 = (size_t)tm * 256, n0 = (size_t)tn * 256;

    int row_r[2], c8s_r[2];
#pragma unroll
    for (int r = 0; r < 2; ++r) {
        int idx = r * 512 + t;
        row_r[r] = idx >> 3;
        c8s_r[r] = (idx & 7) ^ (row_r[r] & 7);
    }

    auto stA = [&](int kt, int bufi, int h) {
#pragma unroll
        for (int r = 0; r < 2; ++r)
            async_load16(A + (m0 + h * 128 + row_r[r]) * (size_t)QK_K + kt * 64 + c8s_r[r] * 8,
                         &As[bufi][(h * 1024 + r * 512 + wid * 64) * 8]);
    };
    auto stB = [&](int kt, int bufi, int h) {
#pragma unroll
        for (int r = 0; r < 2; ++r)
            async_load16(Bt + (n0 + h * 128 + row_r[r]) * (size_t)QK_K + kt * 64 + c8s_r[r] * 8,
                         &Bs[bufi][(h * 1024 + r * 512 + wid * 64) * 8]);
    };

    f32x4 acc[8][4];
#pragma unroll
    for (int i = 0; i < 8; ++i)
#pragma unroll
        for (int j = 0; j < 4; ++j) acc[i][j] = (f32x4){0.f, 0.f, 0.f, 0.f};

    bf16x8 afr[4][2], bf0[2][2], bf1[2][2];

    auto readA = [&](int bufi, int mh) {
#pragma unroll
        for (int i = 0; i < 4; ++i)
#pragma unroll
            for (int kk = 0; kk < 2; ++kk)
                afr[i][kk] = lds_frag(As[bufi], mh * 128 + wr * 64 + i * 16 + lr, kk * 64 + quad * 16);
    };
    auto readB = [&](int bufi, int nh, bf16x8 (&bf)[2][2]) {
#pragma unroll
        for (int j = 0; j < 2; ++j)
#pragma unroll
            for (int kk = 0; kk < 2; ++kk)
                bf[j][kk] = lds_frag(Bs[bufi], nh * 128 + wn * 32 + j * 16 + lr, kk * 64 + quad * 16);
    };

    stA(0, 0, 0); stB(0, 0, 0); stB(0, 0, 1); stA(0, 0, 1);
    asm volatile("s_waitcnt vmcnt(4)" ::: "memory");
    stA(1, 1, 0); stB(1, 1, 0); stB(1, 1, 1);
    asm volatile("s_waitcnt vmcnt(6)" ::: "memory");
    __builtin_amdgcn_s_barrier();

    const int NKT = QK_K / 64;  // 32
    for (int it2 = 0; it2 < 15; ++it2) {
        int tt = 2 * it2;
        readA(0, 0);
        readB(0, 0, bf0);
        stA(tt + 1, 1, 1);
        __builtin_amdgcn_s_barrier();
        asm volatile("s_waitcnt lgkmcnt(0)" ::: "memory");
        __builtin_amdgcn_sched_barrier(0);
        mmaq8<0, 0>(acc, afr, bf0);
        __builtin_amdgcn_s_barrier();
        readB(0, 1, bf1);
        stA(tt + 2, 0, 0);
        __builtin_amdgcn_s_barrier();
        asm volatile("s_waitcnt lgkmcnt(0)" ::: "memory");
        __builtin_amdgcn_sched_barrier(0);
        mmaq8<0, 1>(acc, afr, bf1);
        __builtin_amdgcn_s_barrier();
        readA(0, 1);
        stB(tt + 2, 0, 0);
        __builtin_amdgcn_s_barrier();
        asm volatile("s_waitcnt lgkmcnt(0)" ::: "memory");
        __builtin_amdgcn_sched_barrier(0);
        mmaq8<1, 0>(acc, afr, bf0);
        __builtin_amdgcn_s_barrier();
        stB(tt + 2, 0, 1);
        asm volatile("s_waitcnt vmcnt(6)" ::: "memory");
        __builtin_amdgcn_s_barrier();
        mmaq8<1, 1>(acc, afr, bf1);
        __builtin_amdgcn_s_barrier();
        readA(1, 0);
        readB(1, 0, bf0);
        stA(tt + 2, 0, 1);
        __builtin_amdgcn_s_barrier();
        asm volatile("s_waitcnt lgkmcnt(0)" ::: "memory");
        __builtin_amdgcn_sched_barrier(0);
        mmaq8<0, 0>(acc, afr, bf0);
        __builtin_amdgcn_s_barrier();
        readB(1, 1, bf1);
        stA(tt + 3, 1, 0);
        __builtin_amdgcn_s_barrier();
        asm volatile("s_waitcnt lgkmcnt(0)" ::: "memory");
        __builtin_amdgcn_sched_barrier(0);
        mmaq8<0, 1>(acc, afr, bf1);
        __builtin_amdgcn_s_barrier();
        readA(1, 1);
        stB(tt + 3, 1, 0);
        __builtin_amdgcn_s_barrier();
        asm volatile("s_waitcnt lgkmcnt(0)" ::: "memory");
        __builtin_amdgcn_sched_barrier(0);
        mmaq8<1, 0>(acc, afr, bf0);
        __builtin_amdgcn_s_barrier();
        stB(tt + 3, 1, 1);
        asm volatile("s_waitcnt vmcnt(6)" ::: "memory");
        __builtin_amdgcn_s_barrier();
        mmaq8<1, 1>(acc, afr, bf1);
        __builtin_amdgcn_s_barrier();
    }

    {  // peeled tail: tiles 30 (buf0) and 31 (buf1)
        readA(0, 0);
        readB(0, 0, bf0);
        stA(31, 1, 1);
        __builtin_amdgcn_s_barrier();
        asm volatile("s_waitcnt lgkmcnt(0)" ::: "memory");
        __builtin_amdgcn_sched_barrier(0);
        mmaq8<0, 0>(acc, afr, bf0);
        __builtin_amdgcn_s_barrier();
        readB(0, 1, bf1);
        __builtin_amdgcn_s_barrier();
        asm volatile("s_waitcnt lgkmcnt(0)" ::: "memory");
        __builtin_amdgcn_sched_barrier(0);
        mmaq8<0, 1>(acc, afr, bf1);
        __builtin_amdgcn_s_barrier();
        readA(0, 1);
        __builtin_amdgcn_s_barrier();
        asm volatile("s_waitcnt lgkmcnt(0)" ::: "memory");
        __builtin_amdgcn_sched_barrier(0);
        mmaq8<1, 0>(acc, afr, bf0);
        __builtin_amdgcn_s_barrier();
        asm volatile("s_waitcnt vmcnt(0)" ::: "memory");
        __builtin_amdgcn_s_barrier();
        mmaq8<1, 1>(acc, afr, bf1);
        __builtin_amdgcn_s_barrier();
        readA(1, 0);
        readB(1, 0, bf0);
        asm volatile("s_waitcnt lgkmcnt(0)" ::: "memory");
        __builtin_amdgcn_sched_barrier(0);
        mmaq8<0, 0>(acc, afr, bf0);
        readB(1, 1, bf1);
        asm volatile("s_waitcnt lgkmcnt(0)" ::: "memory");
        __builtin_amdgcn_sched_barrier(0);
        mmaq8<0, 1>(acc, afr, bf1);
        readA(1, 1);
        asm volatile("s_waitcnt lgkmcnt(0)" ::: "memory");
        __builtin_amdgcn_sched_barrier(0);
        mmaq8<1, 0>(acc, afr, bf0);
        mmaq8<1, 1>(acc, afr, bf1);
    }

#pragma unroll
    for (int mh = 0; mh < 2; ++mh)
#pragma unroll
        for (int i = 0; i < 4; ++i)
#pragma unroll
            for (int nh = 0; nh < 2; ++nh)
#pragma unroll
                for (int j = 0; j < 2; ++j)
#pragma unroll
                    for (int r = 0; r < 4; ++r) {
                        size_t row = m0 + mh * 128 + wr * 64 + i * 16 + quad * 4 + r;
                        size_t col = n0 + nh * 128 + wn * 32 + j * 16 + lr;
                        C[row * QK_N + col] = (bf16)acc[mh * 4 + i][nh * 2 + j][r];
                    }
}

// ---------------- flash attention, causal ----------------------------------------
// Round-6 change: 256-thread blocks (4 waves), each wave owns 16 q-rows of the
// 64-row tile (was 2 waves x 32 rows). Same LDS footprint (74 KB) -> 2 blocks/CU
// = 8 waves/CU = 2 waves/SIMD (was 1/SIMD): lgkm/vmcnt stalls now overlap with
// the co-resident wave's MFMA (the m97 co-residency mechanism). Cost: each kf/vf
// read feeds 1 MFMA (was 2) -- overlapped, not serial. VGPR roughly halves;
// __launch_bounds__(256,2) pins 2 waves/EU. All masking/softmax/staging logic
// and the uniform (p, 31-p) pairing are unchanged.
__global__ __launch_bounds__(256, 2) void attn_kernel(const bf16* __restrict__ qkv,
                                                      const bf16* __restrict__ vt,
                                                      bf16* __restrict__ ctx) {
    __shared__ __align__(16) bf16 Ks[2][64 * 128];    // [key][16B-chunk c ^ (key&7)]
    __shared__ __align__(16) bf16 Vts[2][128 * 64];   // [dh][16B-chunk c ^ (dh&7)]
    __shared__ __align__(16) bf16 Ps[4][16][68];      // per-wave P round-trip

    int y = blockIdx.y;
    int p = blockIdx.x;
    int b = y >> 4, h = y & 15;
    int t = threadIdx.x, w = t >> 6, l = t & 63;
    int quad = l >> 4, lr = l & 15;

    const bf16* qbase = qkv + (size_t)b * S_ * QKVN + h * DH_;
    const bf16* kbase = qbase + D_;
    const bf16* vbase = vt + (size_t)y * DH_ * S_;

    const int qtA = p, qtB = 31 - p;
    const int nA = p + 1;  // iters for tile A; total 33

    auto stage = [&](int kt, int bi) {
#pragma unroll
        for (int ii = 0; ii < 4; ++ii) {
            int i = 4 * w + ii;
            int row = 4 * i + (l >> 4);
            int cl = (l & 15) ^ (row & 7);
            async_load16(kbase + (size_t)(kt * 64 + row) * QKVN + cl * 8, Ks[bi] + i * 512);
        }
#pragma unroll
        for (int ii = 0; ii < 4; ++ii) {
            int i = 4 * w + ii;
            int dh = 8 * i + (l >> 3);
            int cl = (l & 7) ^ (dh & 7);
            async_load16(vbase + (size_t)dh * S_ + kt * 64 + cl * 8, Vts[bi] + i * 512);
        }
    };

    const float sc2 = 0.12751745f;  // (1/sqrt(128)) * log2(e), folded into Q

    int qt = qtA, q0 = qt * 64;
    bf16x8 qf[4];
    auto loadQ = [&]() {
#pragma unroll
        for (int kk = 0; kk < 4; ++kk) {
            bf16x8 raw = *(const bf16x8*)(qbase + (size_t)(q0 + w * 16 + lr) * QKVN + kk * 32 + quad * 8);
#pragma unroll
            for (int e = 0; e < 8; ++e) qf[kk][e] = (bf16)((float)raw[e] * sc2);
        }
    };
    loadQ();

    float L_r[4];
    f32x4 o[8];
#pragma unroll
    for (int r = 0; r < 4; ++r) L_r[r] = 0.f;
#pragma unroll
    for (int nt = 0; nt < 8; ++nt) o[nt] = (f32x4){0.f, 0.f, 0.f, 0.f};

    auto epilogue = [&](int q0e) {
#pragma unroll
        for (int d = 1; d < 16; d <<= 1)
#pragma unroll
            for (int r = 0; r < 4; ++r) L_r[r] += __shfl_xor(L_r[r], d, 64);
#pragma unroll
        for (int r = 0; r < 4; ++r) {
            float inv = __builtin_amdgcn_rcpf(L_r[r]);
            int q = q0e + w * 16 + quad * 4 + r;
#pragma unroll
            for (int nt = 0; nt < 8; ++nt)
                ctx[(size_t)(b * S_ + q) * D_ + h * DH_ + nt * 16 + lr] = (bf16)(o[nt][r] * inv);
        }
    };

    stage(0, 0);  // prologue

    for (int it = 0; it < 33; ++it) {
        int buf = it & 1;
        asm volatile("s_waitcnt vmcnt(0)" ::: "memory");
        __syncthreads();
        if (it + 1 < 33) {
            int nit = it + 1;
            int nkt = (nit < nA) ? nit : (nit - nA);
            stage(nkt, buf ^ 1);  // in flight across this iter's compute
        }
        int kt = (it < nA) ? it : (it - nA);

        // S = Q K^T: 16 q-rows x 64 keys per wave
        f32x4 s[4];
#pragma unroll
        for (int jt = 0; jt < 4; ++jt) s[jt] = (f32x4){0.f, 0.f, 0.f, 0.f};
#pragma unroll
        for (int kk = 0; kk < 4; ++kk)
#pragma unroll
            for (int jt = 0; jt < 4; ++jt) {
                bf16x8 kf = *(const bf16x8*)(Ks[buf] + (jt * 16 + lr) * 128 + ((4 * kk + quad) ^ (lr & 7)) * 8);
                s[jt] = __builtin_amdgcn_mfma_f32_16x16x32_bf16(qf[kk], kf, s[jt], 0, 0, 0);
            }

        // exp2 (m=0) + mask (diag k-tile only) + per-lane L accumulation + P store
        bool diag = (kt == qt);
#pragma unroll
        for (int jt = 0; jt < 4; ++jt) {
            int keyi = jt * 16 + lr;
#pragma unroll
            for (int r = 0; r < 4; ++r) {
                float s2 = s[jt][r];
                if (diag && keyi > w * 16 + quad * 4 + r) s2 = -3.0e38f;
                float pv = __builtin_amdgcn_exp2f(s2);
                s[jt][r] = pv;
                L_r[r] += pv;
            }
        }
#pragma unroll
        for (int jt = 0; jt < 4; ++jt)
#pragma unroll
            for (int r = 0; r < 4; ++r)
                Ps[w][quad * 4 + r][jt * 16 + lr] = (bf16)s[jt][r];
        asm volatile("s_waitcnt lgkmcnt(0)" ::: "memory");  // per-wave Ps region

        // O += P @ V
#pragma unroll
        for (int ks = 0; ks < 2; ++ks) {
            const bf16* pp = &Ps[w][lr][ks * 32 + quad * 8];
            bf16x4 lo = *(const bf16x4*)pp;
            bf16x4 hi = *(const bf16x4*)(pp + 4);
            bf16x8 pf = __builtin_shufflevector(lo, hi, 0, 1, 2, 3, 4, 5, 6, 7);
#pragma unroll
            for (int nt = 0; nt < 8; ++nt) {
                bf16x8 vf = *(const bf16x8*)(Vts[buf] + (nt * 16 + lr) * 64 + ((4 * ks + quad) ^ (lr & 7)) * 8);
                o[nt] = __builtin_amdgcn_mfma_f32_16x16x32_bf16(pf, vf, o[nt], 0, 0, 0);
            }
        }

        // tile switch A -> B after A's diagonal iteration
        if (it == nA - 1) {
            epilogue(q0);
            qt = qtB;
            q0 = qt * 64;
            loadQ();
#pragma unroll
            for (int r = 0; r < 4; ++r) L_r[r] = 0.f;
#pragma unroll
            for (int nt = 0; nt < 8; ++nt) o[nt] = (f32x4){0.f, 0.f, 0.f, 0.f};
        }
    }

    epilogue(q0);  // tile B
}

extern "C" void kernel_launch(void* const* d_in, const int* in_sizes, int n_in,
                              void* d_out, int out_size, void* d_ws, size_t ws_size,
                              hipStream_t stream) {
    const float* x  = (const float*)d_in[0];
    const float* Wq = (const float*)d_in[1];
    const float* Wk = (const float*)d_in[2];
    const float* Wv = (const float*)d_in[3];
    const float* Wo = (const float*)d_in[4];
    float* out = (float*)d_out;

    char* ws = (char*)d_ws;
    bf16* WqkvT = (bf16*)(ws);                       // 3*2048*2048*2 = 25165824
    bf16* WoT   = (bf16*)(ws + 25165824);            // 2048*2048*2   =  8388608
    bf16* qkv   = (bf16*)(ws + 33554432);            // 4096*6144*2   = 50331648
    bf16* vt    = (bf16*)(ws + 83886080);            // 32*128*2048*2 = 16777216
    bf16* ctx   = (bf16*)(ws + 100663296);           // 4096*2048*2   = 16777216
    bf16* xb    = (bf16*)(ws + 117440512);           // 4096*2048*2   = 16777216
    // total ws use: 134217728 bytes (128 MiB)

    cvt_kernel<<<4096, 256, 0, stream>>>(x, xb);
    wtrans_kernel<<<dim3(32, 32, 4), 256, 0, stream>>>(Wq, Wk, Wv, Wo, WqkvT, WoT);
    gemm_qkv<<<dim3(384), 512, 0, stream>>>(xb, WqkvT, qkv);
    vtrans_kernel<<<dim3(32, 2, 32), 256, 0, stream>>>(qkv, vt);
    attn_kernel<<<dim3(16, 32), 256, 0, stream>>>(qkv, vt, ctx);
    gemm_bt<float><<<dim3(16, 32), 256, 0, stream>>>(ctx, WoT, out, B_ * S_, D_, D_);
}

// Round 7
// 393.409 us; speedup vs baseline: 1.1183x; 1.0199x over previous
//
#include <hip/hip_runtime.h>

typedef __bf16 bf16;
typedef __bf16 bf16x4 __attribute__((ext_vector_type(4)));
typedef __bf16 bf16x8 __attribute__((ext_vector_type(8)));
typedef float f32x4 __attribute__((ext_vector_type(4)));

#define B_ 2
#define S_ 2048
#define D_ 2048
#define H_ 16
#define DH_ 128
#define QKVN 6144

__device__ __forceinline__ void async_load16(const bf16* g, bf16* l) {
    __builtin_amdgcn_global_load_lds((const __attribute__((address_space(1))) void*)g,
                                     (__attribute__((address_space(3))) void*)l, 16, 0, 0);
}

__device__ __forceinline__ unsigned int bf16_bits(float x) {
    bf16 h = (bf16)x;
    return (unsigned int)__builtin_bit_cast(unsigned short, h);
}

// ---------------- x cast: f32 -> bf16, 8 elems/thread -----------------------------
__global__ __launch_bounds__(256) void cvt_kernel(const float* __restrict__ src,
                                                  bf16* __restrict__ dst) {
    size_t i = (size_t)blockIdx.x * 256 + threadIdx.x;
    const float4* s = (const float4*)src;
    float4 a = s[2 * i], b = s[2 * i + 1];
    bf16x8 o;
    o[0] = (bf16)a.x; o[1] = (bf16)a.y; o[2] = (bf16)a.z; o[3] = (bf16)a.w;
    o[4] = (bf16)b.x; o[5] = (bf16)b.y; o[6] = (bf16)b.z; o[7] = (bf16)b.w;
    *(bf16x8*)(dst + 8 * i) = o;
}

// ------- weight transpose + cast: W[K][N] f32 -> Wt[N][K] bf16, 4 matrices --------
__global__ __launch_bounds__(256) void wtrans_kernel(const float* __restrict__ Wq,
                                                     const float* __restrict__ Wk,
                                                     const float* __restrict__ Wv,
                                                     const float* __restrict__ Wo,
                                                     bf16* __restrict__ WqkvT,
                                                     bf16* __restrict__ WoT) {
    __shared__ unsigned int tile[64][65];  // bf16 bits in low half
    int z = blockIdx.z;
    const float* src = (z == 0) ? Wq : (z == 1) ? Wk : (z == 2) ? Wv : Wo;
    bf16* dst = (z < 3) ? (WqkvT + (size_t)z * D_ * D_) : WoT;
    int r0 = blockIdx.y * 64, c0 = blockIdx.x * 64;
    int t = threadIdx.x;
    int tr = t >> 4, tc4 = (t & 15) * 4;
#pragma unroll
    for (int it = 0; it < 4; ++it) {
        int r = it * 16 + tr;
        float4 v = *(const float4*)(src + (size_t)(r0 + r) * D_ + c0 + tc4);
        tile[r][tc4 + 0] = bf16_bits(v.x);
        tile[r][tc4 + 1] = bf16_bits(v.y);
        tile[r][tc4 + 2] = bf16_bits(v.z);
        tile[r][tc4 + 3] = bf16_bits(v.w);
    }
    __syncthreads();
#pragma unroll
    for (int it = 0; it < 4; ++it) {
        int a = it * 16 + tr;
        unsigned u0 = tile[tc4 + 0][a], u1 = tile[tc4 + 1][a];
        unsigned u2 = tile[tc4 + 2][a], u3 = tile[tc4 + 3][a];
        uint2 v;
        v.x = (u0 & 0xffffu) | (u1 << 16);
        v.y = (u2 & 0xffffu) | (u3 << 16);
        *(uint2*)(dst + (size_t)(c0 + a) * D_ + r0 + tc4) = v;
    }
}

// ---------------- V transpose: qkv[:,4096+h*128+dh] -> vt[bh][dh][s], bf16 --------
__global__ __launch_bounds__(256) void vtrans_kernel(const bf16* __restrict__ qkv,
                                                     bf16* __restrict__ vt) {
    __shared__ unsigned int tile[64][65];
    int bh = blockIdx.z;
    int b = bh >> 4, h = bh & 15;
    int s0 = blockIdx.x * 64, d0 = blockIdx.y * 64;
    int t = threadIdx.x, tr = t >> 4, tc4 = (t & 15) * 4;
#pragma unroll
    for (int it = 0; it < 4; ++it) {
        int r = it * 16 + tr;  // s offset
        uint2 v = *(const uint2*)(qkv + (size_t)(b * S_ + s0 + r) * QKVN + 2 * D_ + h * DH_ + d0 + tc4);
        tile[r][tc4 + 0] = v.x & 0xffffu;
        tile[r][tc4 + 1] = v.x >> 16;
        tile[r][tc4 + 2] = v.y & 0xffffu;
        tile[r][tc4 + 3] = v.y >> 16;
    }
    __syncthreads();
#pragma unroll
    for (int it = 0; it < 4; ++it) {
        int a = it * 16 + tr;  // dh offset
        unsigned u0 = tile[tc4 + 0][a], u1 = tile[tc4 + 1][a];
        unsigned u2 = tile[tc4 + 2][a], u3 = tile[tc4 + 3][a];
        uint2 v;
        v.x = (u0 & 0xffffu) | (u1 << 16);
        v.y = (u2 & 0xffffu) | (u3 << 16);
        *(uint2*)(vt + (size_t)bh * DH_ * S_ + (size_t)(d0 + a) * S_ + s0 + tc4) = v;
    }
}

// ---------------- m97-style GEMM: C[M][N] = A[M][K] @ Bt[N][K]^T ------------------
template <typename CT>
__global__ __launch_bounds__(256) void gemm_bt(const bf16* __restrict__ A,
                                               const bf16* __restrict__ Bt,
                                               CT* __restrict__ C,
                                               int M, int N, int K) {
    __shared__ __align__(16) bf16 As[128 * 32];
    __shared__ __align__(16) bf16 Bs[128 * 32];
    int t = threadIdx.x;
    int w = t >> 6, l = t & 63;
    int quad = l >> 4, lr = l & 15;
    int wr = w >> 1, wc = w & 1;
    size_t m0 = (size_t)blockIdx.y * 128, n0 = (size_t)blockIdx.x * 128;
    int srow = l >> 2, scol = (l & 3) * 8;

    f32x4 acc[4][4];
#pragma unroll
    for (int i = 0; i < 4; ++i)
#pragma unroll
        for (int j = 0; j < 4; ++j) acc[i][j] = (f32x4){0.f, 0.f, 0.f, 0.f};

    for (int k0 = 0; k0 < K; k0 += 32) {
        __syncthreads();
#pragma unroll
        for (int i = 0; i < 2; ++i) {
            int c = w * 2 + i;
            async_load16(A + (m0 + c * 16 + srow) * (size_t)K + k0 + scol, As + c * 512);
            async_load16(Bt + (n0 + c * 16 + srow) * (size_t)K + k0 + scol, Bs + c * 512);
        }
        asm volatile("s_waitcnt vmcnt(0)" ::: "memory");
        __syncthreads();
        bf16x8 af[4], bfr[4];
#pragma unroll
        for (int i = 0; i < 4; ++i) af[i] = *(const bf16x8*)(As + (wr * 64 + i * 16 + lr) * 32 + quad * 8);
#pragma unroll
        for (int j = 0; j < 4; ++j) bfr[j] = *(const bf16x8*)(Bs + (wc * 64 + j * 16 + lr) * 32 + quad * 8);
#pragma unroll
        for (int i = 0; i < 4; ++i)
#pragma unroll
            for (int j = 0; j < 4; ++j)
                acc[i][j] = __builtin_amdgcn_mfma_f32_16x16x32_bf16(af[i], bfr[j], acc[i][j], 0, 0, 0);
    }

    size_t bm = m0 + wr * 64 + quad * 4;
    size_t bn = n0 + wc * 64 + lr;
#pragma unroll
    for (int i = 0; i < 4; ++i)
#pragma unroll
        for (int j = 0; j < 4; ++j)
#pragma unroll
            for (int r = 0; r < 4; ++r)
                C[(bm + i * 16 + r) * (size_t)N + bn + j * 16] = (CT)acc[i][j][r];
}

// ========== 256x128-tile GEMM for QKV: C[4096][6144] = A[4096][2048] @ Bt^T =======
// Round-7 change: tile 256x128 -> grid 16x48 = 768 blocks = EXACTLY 3 scheduling
// rounds at 1 block/CU (r5's 384 blocks = 1.5 rounds wasted 25% of CU-time).
// Same schedule DNA as r5 (conflict-free chunk-XOR swizzle, one-half-per-phase
// staging, counted vmcnt before barriers, setprio MFMA clusters, lgkm0+schedbar).
// 2 phases per K-tile (mh=0/1, 16 MFMA each); 4-phase prefetch cover preserved
// via 3-buffer LDS rotation (144 KB): compute tile kt from buf kt%3 while
// staging tile kt+2 into buf (kt+2)%3.
// Outstanding-loads ledger (per-tile issue order B,A0,A1; 2 vmcnt units/call):
//   steady state 12 outstanding at each wait;
//   ph0 end: vmcnt(10) retires A1(kt)        [issued kt-2 ph1, cover 4 phases]
//   ph1 end: vmcnt(8)  retires B,A0(kt+1)    [issued kt-1 ph0, cover 3 phases]
//   prologue: stage tiles 0,1 fully -> vmcnt(8) = B,A0(0) resident
//   tail (tiles 30,31, no staging): vmcnt 6 -> 2 -> 0.
// Overwrite safety: buf (kt+2)%3 last read at tile kt-1 ph1; those ds_reads
// complete (lgkm0) before the barrier preceding kt ph0's stage issue.
#define QK_K 2048
#define QK_N 6144

__device__ __forceinline__ bf16x8 lds_frag(const bf16* tile, int row, int colByte) {
    int off = row * 128 + (colByte ^ ((row & 7) << 4));
    return *(const bf16x8*)((const char*)tile + off);
}

template <int MH>
__device__ __forceinline__ void mmaq16(f32x4 (&acc)[8][2], const bf16x8 (&afr)[4][2],
                                       const bf16x8 (&bf)[2][2]) {
    __builtin_amdgcn_s_setprio(1);
#pragma unroll
    for (int i = 0; i < 4; ++i)
#pragma unroll
        for (int j = 0; j < 2; ++j)
#pragma unroll
            for (int kk = 0; kk < 2; ++kk)
                acc[MH * 4 + i][j] = __builtin_amdgcn_mfma_f32_16x16x32_bf16(
                    afr[i][kk], bf[j][kk], acc[MH * 4 + i][j], 0, 0, 0);
    __builtin_amdgcn_s_setprio(0);
}

__global__ __launch_bounds__(512, 2) void gemm_qkv(const bf16* __restrict__ A,
                                                   const bf16* __restrict__ Bt,
                                                   bf16* __restrict__ C) {
    __shared__ __align__(16) bf16 As[3][256 * 64];  // 96 KB
    __shared__ __align__(16) bf16 Bs[3][128 * 64];  // 48 KB

    int t = threadIdx.x;
    int wid = t >> 6, lane = t & 63;
    int quad = lane >> 4, lr = lane & 15;
    int wr = wid >> 2, wn = wid & 3;  // 2 (M) x 4 (N) wave grid

    // XCD swizzle: 768 wgs = 8 XCDs x 96; column-major -> each XCD owns 6
    // disjoint B-panels (128 cols x K = 512 KB, L2-resident), A streams via L3.
    int bid = blockIdx.x;
    int swz = (bid & 7) * 96 + (bid >> 3);
    int tn = swz >> 4, tm = swz & 15;
    size_t m0 = (size_t)tm * 256, n0 = (size_t)tn * 128;

    // staging geometry: chunk idx = r*512 + t; row = idx>>3 in [0,128),
    // col-chunk = idx&7; source col-chunk permuted by row&7 (inverse of read XOR).
    int row_r[2], c8s_r[2];
#pragma unroll
    for (int r = 0; r < 2; ++r) {
        int idx = r * 512 + t;
        row_r[r] = idx >> 3;
        c8s_r[r] = (idx & 7) ^ (row_r[r] & 7);
    }

    auto stA = [&](int kt, int bufi, int h) {  // one 128-row half of the A tile
#pragma unroll
        for (int r = 0; r < 2; ++r)
            async_load16(A + (m0 + h * 128 + row_r[r]) * (size_t)QK_K + kt * 64 + c8s_r[r] * 8,
                         &As[bufi][(h * 1024 + r * 512 + wid * 64) * 8]);
    };
    auto stB = [&](int kt, int bufi) {  // full 128-row B tile
#pragma unroll
        for (int r = 0; r < 2; ++r)
            async_load16(Bt + (n0 + row_r[r]) * (size_t)QK_K + kt * 64 + c8s_r[r] * 8,
                         &Bs[bufi][(r * 512 + wid * 64) * 8]);
    };

    f32x4 acc[8][2];
#pragma unroll
    for (int i = 0; i < 8; ++i)
#pragma unroll
        for (int j = 0; j < 2; ++j) acc[i][j] = (f32x4){0.f, 0.f, 0.f, 0.f};

    bf16x8 afr[4][2], bf[2][2];

    auto readA = [&](int bufi, int mh) {
#pragma unroll
        for (int i = 0; i < 4; ++i)
#pragma unroll
            for (int kk = 0; kk < 2; ++kk)
                afr[i][kk] = lds_frag(As[bufi], mh * 128 + wr * 64 + i * 16 + lr, kk * 64 + quad * 16);
    };
    auto readB = [&](int bufi) {
#pragma unroll
        for (int j = 0; j < 2; ++j)
#pragma unroll
            for (int kk = 0; kk < 2; ++kk)
                bf[j][kk] = lds_frag(Bs[bufi], wn * 32 + j * 16 + lr, kk * 64 + quad * 16);
    };

    // prologue: stage tiles 0 and 1 (order per tile: B, A0, A1)
    stB(0, 0); stA(0, 0, 0); stA(0, 0, 1);
    stB(1, 1); stA(1, 1, 0); stA(1, 1, 1);
    asm volatile("s_waitcnt vmcnt(8)" ::: "memory");  // B,A0(0) resident
    __builtin_amdgcn_s_barrier();

    auto tile2ph = [&](int kt, int cb, int nb2) {
        // ph0: quad mh=0; stage B,A0(kt+2)
        readA(cb, 0);
        readB(cb);
        stB(kt + 2, nb2);
        stA(kt + 2, nb2, 0);
        __builtin_amdgcn_s_barrier();
        asm volatile("s_waitcnt lgkmcnt(0)" ::: "memory");
        __builtin_amdgcn_sched_barrier(0);
        mmaq16<0>(acc, afr, bf);
        asm volatile("s_waitcnt vmcnt(10)" ::: "memory");  // A1(kt) resident
        __builtin_amdgcn_s_barrier();
        // ph1: quad mh=1; stage A1(kt+2)
        readA(cb, 1);
        stA(kt + 2, nb2, 1);
        __builtin_amdgcn_s_barrier();
        asm volatile("s_waitcnt lgkmcnt(0)" ::: "memory");
        __builtin_amdgcn_sched_barrier(0);
        mmaq16<1>(acc, afr, bf);
        asm volatile("s_waitcnt vmcnt(8)" ::: "memory");  // B,A0(kt+1) resident
        __builtin_amdgcn_s_barrier();
    };

    // tiles 0..29 (stages tiles 2..31); 30 % 3 == 0 so buffer pattern repeats
    for (int kt3 = 0; kt3 < 30; kt3 += 3) {
        tile2ph(kt3 + 0, 0, 2);
        tile2ph(kt3 + 1, 1, 0);
        tile2ph(kt3 + 2, 2, 1);
    }

    {  // tail: tiles 30 (buf0) and 31 (buf1), no staging; drain 8 -> 0
        readA(0, 0);
        readB(0);
        __builtin_amdgcn_s_barrier();
        asm volatile("s_waitcnt lgkmcnt(0)" ::: "memory");
        __builtin_amdgcn_sched_barrier(0);
        mmaq16<0>(acc, afr, bf);
        asm volatile("s_waitcnt vmcnt(6)" ::: "memory");  // A1(30) resident
        __builtin_amdgcn_s_barrier();
        readA(0, 1);
        __builtin_amdgcn_s_barrier();
        asm volatile("s_waitcnt lgkmcnt(0)" ::: "memory");
        __builtin_amdgcn_sched_barrier(0);
        mmaq16<1>(acc, afr, bf);
        asm volatile("s_waitcnt vmcnt(2)" ::: "memory");  // B,A0(31) resident
        __builtin_amdgcn_s_barrier();
        readA(1, 0);
        readB(1);
        __builtin_amdgcn_s_barrier();
        asm volatile("s_waitcnt lgkmcnt(0)" ::: "memory");
        __builtin_amdgcn_sched_barrier(0);
        mmaq16<0>(acc, afr, bf);
        asm volatile("s_waitcnt vmcnt(0)" ::: "memory");  // A1(31) resident
        __builtin_amdgcn_s_barrier();
        readA(1, 1);
        asm volatile("s_waitcnt lgkmcnt(0)" ::: "memory");
        __builtin_amdgcn_sched_barrier(0);
        mmaq16<1>(acc, afr, bf);
    }

    // epilogue: C/D layout col=lr, row=quad*4+r per 16x16 frag
#pragma unroll
    for (int mh = 0; mh < 2; ++mh)
#pragma unroll
        for (int i = 0; i < 4; ++i)
#pragma unroll
            for (int j = 0; j < 2; ++j)
#pragma unroll
                for (int r = 0; r < 4; ++r) {
                    size_t row = m0 + mh * 128 + wr * 64 + i * 16 + quad * 4 + r;
                    size_t col = n0 + wn * 32 + j * 16 + lr;
                    C[row * QK_N + col] = (bf16)acc[mh * 4 + i][j][r];
                }
}

// ---------------- flash attention, causal (r6 4-wave version, kept) ---------------
__global__ __launch_bounds__(256, 2) void attn_kernel(const bf16* __restrict__ qkv,
                                                      const bf16* __restrict__ vt,
                                                      bf16* __restrict__ ctx) {
    __shared__ __align__(16) bf16 Ks[2][64 * 128];    // [key][16B-chunk c ^ (key&7)]
    __shared__ __align__(16) bf16 Vts[2][128 * 64];   // [dh][16B-chunk c ^ (dh&7)]
    __shared__ __align__(16) bf16 Ps[4][16][68];      // per-wave P round-trip

    int y = blockIdx.y;
    int p = blockIdx.x;
    int b = y >> 4, h = y & 15;
    int t = threadIdx.x, w = t >> 6, l = t & 63;
    int quad = l >> 4, lr = l & 15;

    const bf16* qbase = qkv + (size_t)b * S_ * QKVN + h * DH_;
    const bf16* kbase = qbase + D_;
    const bf16* vbase = vt + (size_t)y * DH_ * S_;

    const int qtA = p, qtB = 31 - p;
    const int nA = p + 1;  // iters for tile A; total 33

    auto stage = [&](int kt, int bi) {
#pragma unroll
        for (int ii = 0; ii < 4; ++ii) {
            int i = 4 * w + ii;
            int row = 4 * i + (l >> 4);
            int cl = (l & 15) ^ (row & 7);
            async_load16(kbase + (size_t)(kt * 64 + row) * QKVN + cl * 8, Ks[bi] + i * 512);
        }
#pragma unroll
        for (int ii = 0; ii < 4; ++ii) {
            int i = 4 * w + ii;
            int dh = 8 * i + (l >> 3);
            int cl = (l & 7) ^ (dh & 7);
            async_load16(vbase + (size_t)dh * S_ + kt * 64 + cl * 8, Vts[bi] + i * 512);
        }
    };

    const float sc2 = 0.12751745f;  // (1/sqrt(128)) * log2(e), folded into Q

    int qt = qtA, q0 = qt * 64;
    bf16x8 qf[4];
    auto loadQ = [&]() {
#pragma unroll
        for (int kk = 0; kk < 4; ++kk) {
            bf16x8 raw = *(const bf16x8*)(qbase + (size_t)(q0 + w * 16 + lr) * QKVN + kk * 32 + quad * 8);
#pragma unroll
            for (int e = 0; e < 8; ++e) qf[kk][e] = (bf16)((float)raw[e] * sc2);
        }
    };
    loadQ();

    float L_r[4];
    f32x4 o[8];
#pragma unroll
    for (int r = 0; r < 4; ++r) L_r[r] = 0.f;
#pragma unroll
    for (int nt = 0; nt < 8; ++nt) o[nt] = (f32x4){0.f, 0.f, 0.f, 0.f};

    auto epilogue = [&](int q0e) {
#pragma unroll
        for (int d = 1; d < 16; d <<= 1)
#pragma unroll
            for (int r = 0; r < 4; ++r) L_r[r] += __shfl_xor(L_r[r], d, 64);
#pragma unroll
        for (int r = 0; r < 4; ++r) {
            float inv = __builtin_amdgcn_rcpf(L_r[r]);
            int q = q0e + w * 16 + quad * 4 + r;
#pragma unroll
            for (int nt = 0; nt < 8; ++nt)
                ctx[(size_t)(b * S_ + q) * D_ + h * DH_ + nt * 16 + lr] = (bf16)(o[nt][r] * inv);
        }
    };

    stage(0, 0);  // prologue

    for (int it = 0; it < 33; ++it) {
        int buf = it & 1;
        asm volatile("s_waitcnt vmcnt(0)" ::: "memory");
        __syncthreads();
        if (it + 1 < 33) {
            int nit = it + 1;
            int nkt = (nit < nA) ? nit : (nit - nA);
            stage(nkt, buf ^ 1);  // in flight across this iter's compute
        }
        int kt = (it < nA) ? it : (it - nA);

        // S = Q K^T: 16 q-rows x 64 keys per wave
        f32x4 s[4];
#pragma unroll
        for (int jt = 0; jt < 4; ++jt) s[jt] = (f32x4){0.f, 0.f, 0.f, 0.f};
#pragma unroll
        for (int kk = 0; kk < 4; ++kk)
#pragma unroll
            for (int jt = 0; jt < 4; ++jt) {
                bf16x8 kf = *(const bf16x8*)(Ks[buf] + (jt * 16 + lr) * 128 + ((4 * kk + quad) ^ (lr & 7)) * 8);
                s[jt] = __builtin_amdgcn_mfma_f32_16x16x32_bf16(qf[kk], kf, s[jt], 0, 0, 0);
            }

        // exp2 (m=0) + mask (diag k-tile only) + per-lane L accumulation + P store
        bool diag = (kt == qt);
#pragma unroll
        for (int jt = 0; jt < 4; ++jt) {
            int keyi = jt * 16 + lr;
#pragma unroll
            for (int r = 0; r < 4; ++r) {
                float s2 = s[jt][r];
                if (diag && keyi > w * 16 + quad * 4 + r) s2 = -3.0e38f;
                float pv = __builtin_amdgcn_exp2f(s2);
                s[jt][r] = pv;
                L_r[r] += pv;
            }
        }
#pragma unroll
        for (int jt = 0; jt < 4; ++jt)
#pragma unroll
            for (int r = 0; r < 4; ++r)
                Ps[w][quad * 4 + r][jt * 16 + lr] = (bf16)s[jt][r];
        asm volatile("s_waitcnt lgkmcnt(0)" ::: "memory");  // per-wave Ps region

        // O += P @ V
#pragma unroll
        for (int ks = 0; ks < 2; ++ks) {
            const bf16* pp = &Ps[w][lr][ks * 32 + quad * 8];
            bf16x4 lo = *(const bf16x4*)pp;
            bf16x4 hi = *(const bf16x4*)(pp + 4);
            bf16x8 pf = __builtin_shufflevector(lo, hi, 0, 1, 2, 3, 4, 5, 6, 7);
#pragma unroll
            for (int nt = 0; nt < 8; ++nt) {
                bf16x8 vf = *(const bf16x8*)(Vts[buf] + (nt * 16 + lr) * 64 + ((4 * ks + quad) ^ (lr & 7)) * 8);
                o[nt] = __builtin_amdgcn_mfma_f32_16x16x32_bf16(pf, vf, o[nt], 0, 0, 0);
            }
        }

        // tile switch A -> B after A's diagonal iteration
        if (it == nA - 1) {
            epilogue(q0);
            qt = qtB;
            q0 = qt * 64;
            loadQ();
#pragma unroll
            for (int r = 0; r < 4; ++r) L_r[r] = 0.f;
#pragma unroll
            for (int nt = 0; nt < 8; ++nt) o[nt] = (f32x4){0.f, 0.f, 0.f, 0.f};
        }
    }

    epilogue(q0);  // tile B
}

extern "C" void kernel_launch(void* const* d_in, const int* in_sizes, int n_in,
                              void* d_out, int out_size, void* d_ws, size_t ws_size,
                              hipStream_t stream) {
    const float* x  = (const float*)d_in[0];
    const float* Wq = (const float*)d_in[1];
    const float* Wk = (const float*)d_in[2];
    const float* Wv = (const float*)d_in[3];
    const float* Wo = (const float*)d_in[4];
    float* out = (float*)d_out;

    char* ws = (char*)d_ws;
    bf16* WqkvT = (bf16*)(ws);                       // 3*2048*2048*2 = 25165824
    bf16* WoT   = (bf16*)(ws + 25165824);            // 2048*2048*2   =  8388608
    bf16* qkv   = (bf16*)(ws + 33554432);            // 4096*6144*2   = 50331648
    bf16* vt    = (bf16*)(ws + 83886080);            // 32*128*2048*2 = 16777216
    bf16* ctx   = (bf16*)(ws + 100663296);           // 4096*2048*2   = 16777216
    bf16* xb    = (bf16*)(ws + 117440512);           // 4096*2048*2   = 16777216
    // total ws use: 134217728 bytes (128 MiB)

    cvt_kernel<<<4096, 256, 0, stream>>>(x, xb);
    wtrans_kernel<<<dim3(32, 32, 4), 256, 0, stream>>>(Wq, Wk, Wv, Wo, WqkvT, WoT);
    gemm_qkv<<<dim3(768), 512, 0, stream>>>(xb, WqkvT, qkv);
    vtrans_kernel<<<dim3(32, 2, 32), 256, 0, stream>>>(qkv, vt);
    attn_kernel<<<dim3(16, 32), 256, 0, stream>>>(qkv, vt, ctx);
    gemm_bt<float><<<dim3(16, 32), 256, 0, stream>>>(ctx, WoT, out, B_ * S_, D_, D_);
}

// Round 8
// 382.102 us; speedup vs baseline: 1.1513x; 1.0296x over previous
//
#include <hip/hip_runtime.h>

typedef __bf16 bf16;
typedef __bf16 bf16x4 __attribute__((ext_vector_type(4)));
typedef __bf16 bf16x8 __attribute__((ext_vector_type(8)));
typedef float f32x4 __attribute__((ext_vector_type(4)));

#define B_ 2
#define S_ 2048
#define D_ 2048
#define H_ 16
#define DH_ 128
#define QKVN 6144

__device__ __forceinline__ void async_load16(const bf16* g, bf16* l) {
    __builtin_amdgcn_global_load_lds((const __attribute__((address_space(1))) void*)g,
                                     (__attribute__((address_space(3))) void*)l, 16, 0, 0);
}

__device__ __forceinline__ unsigned int bf16_bits(float x) {
    bf16 h = (bf16)x;
    return (unsigned int)__builtin_bit_cast(unsigned short, h);
}

// ---------------- x cast: f32 -> bf16, 8 elems/thread -----------------------------
__global__ __launch_bounds__(256) void cvt_kernel(const float* __restrict__ src,
                                                  bf16* __restrict__ dst) {
    size_t i = (size_t)blockIdx.x * 256 + threadIdx.x;
    const float4* s = (const float4*)src;
    float4 a = s[2 * i], b = s[2 * i + 1];
    bf16x8 o;
    o[0] = (bf16)a.x; o[1] = (bf16)a.y; o[2] = (bf16)a.z; o[3] = (bf16)a.w;
    o[4] = (bf16)b.x; o[5] = (bf16)b.y; o[6] = (bf16)b.z; o[7] = (bf16)b.w;
    *(bf16x8*)(dst + 8 * i) = o;
}

// ------- weight transpose + cast: W[K][N] f32 -> Wt[N][K] bf16, 4 matrices --------
__global__ __launch_bounds__(256) void wtrans_kernel(const float* __restrict__ Wq,
                                                     const float* __restrict__ Wk,
                                                     const float* __restrict__ Wv,
                                                     const float* __restrict__ Wo,
                                                     bf16* __restrict__ WqkvT,
                                                     bf16* __restrict__ WoT) {
    __shared__ unsigned int tile[64][65];  // bf16 bits in low half
    int z = blockIdx.z;
    const float* src = (z == 0) ? Wq : (z == 1) ? Wk : (z == 2) ? Wv : Wo;
    bf16* dst = (z < 3) ? (WqkvT + (size_t)z * D_ * D_) : WoT;
    int r0 = blockIdx.y * 64, c0 = blockIdx.x * 64;
    int t = threadIdx.x;
    int tr = t >> 4, tc4 = (t & 15) * 4;
#pragma unroll
    for (int it = 0; it < 4; ++it) {
        int r = it * 16 + tr;
        float4 v = *(const float4*)(src + (size_t)(r0 + r) * D_ + c0 + tc4);
        tile[r][tc4 + 0] = bf16_bits(v.x);
        tile[r][tc4 + 1] = bf16_bits(v.y);
        tile[r][tc4 + 2] = bf16_bits(v.z);
        tile[r][tc4 + 3] = bf16_bits(v.w);
    }
    __syncthreads();
#pragma unroll
    for (int it = 0; it < 4; ++it) {
        int a = it * 16 + tr;
        unsigned u0 = tile[tc4 + 0][a], u1 = tile[tc4 + 1][a];
        unsigned u2 = tile[tc4 + 2][a], u3 = tile[tc4 + 3][a];
        uint2 v;
        v.x = (u0 & 0xffffu) | (u1 << 16);
        v.y = (u2 & 0xffffu) | (u3 << 16);
        *(uint2*)(dst + (size_t)(c0 + a) * D_ + r0 + tc4) = v;
    }
}

// ---------------- V transpose: qkv[:,4096+h*128+dh] -> vt[bh][dh][s], bf16 --------
__global__ __launch_bounds__(256) void vtrans_kernel(const bf16* __restrict__ qkv,
                                                     bf16* __restrict__ vt) {
    __shared__ unsigned int tile[64][65];
    int bh = blockIdx.z;
    int b = bh >> 4, h = bh & 15;
    int s0 = blockIdx.x * 64, d0 = blockIdx.y * 64;
    int t = threadIdx.x, tr = t >> 4, tc4 = (t & 15) * 4;
#pragma unroll
    for (int it = 0; it < 4; ++it) {
        int r = it * 16 + tr;  // s offset
        uint2 v = *(const uint2*)(qkv + (size_t)(b * S_ + s0 + r) * QKVN + 2 * D_ + h * DH_ + d0 + tc4);
        tile[r][tc4 + 0] = v.x & 0xffffu;
        tile[r][tc4 + 1] = v.x >> 16;
        tile[r][tc4 + 2] = v.y & 0xffffu;
        tile[r][tc4 + 3] = v.y >> 16;
    }
    __syncthreads();
#pragma unroll
    for (int it = 0; it < 4; ++it) {
        int a = it * 16 + tr;  // dh offset
        unsigned u0 = tile[tc4 + 0][a], u1 = tile[tc4 + 1][a];
        unsigned u2 = tile[tc4 + 2][a], u3 = tile[tc4 + 3][a];
        uint2 v;
        v.x = (u0 & 0xffffu) | (u1 << 16);
        v.y = (u2 & 0xffffu) | (u3 << 16);
        *(uint2*)(vt + (size_t)bh * DH_ * S_ + (size_t)(d0 + a) * S_ + s0 + tc4) = v;
    }
}

// ---------------- m97-style GEMM: C[M][N] = A[M][K] @ Bt[N][K]^T ------------------
template <typename CT>
__global__ __launch_bounds__(256) void gemm_bt(const bf16* __restrict__ A,
                                               const bf16* __restrict__ Bt,
                                               CT* __restrict__ C,
                                               int M, int N, int K) {
    __shared__ __align__(16) bf16 As[128 * 32];
    __shared__ __align__(16) bf16 Bs[128 * 32];
    int t = threadIdx.x;
    int w = t >> 6, l = t & 63;
    int quad = l >> 4, lr = l & 15;
    int wr = w >> 1, wc = w & 1;
    size_t m0 = (size_t)blockIdx.y * 128, n0 = (size_t)blockIdx.x * 128;
    int srow = l >> 2, scol = (l & 3) * 8;

    f32x4 acc[4][4];
#pragma unroll
    for (int i = 0; i < 4; ++i)
#pragma unroll
        for (int j = 0; j < 4; ++j) acc[i][j] = (f32x4){0.f, 0.f, 0.f, 0.f};

    for (int k0 = 0; k0 < K; k0 += 32) {
        __syncthreads();
#pragma unroll
        for (int i = 0; i < 2; ++i) {
            int c = w * 2 + i;
            async_load16(A + (m0 + c * 16 + srow) * (size_t)K + k0 + scol, As + c * 512);
            async_load16(Bt + (n0 + c * 16 + srow) * (size_t)K + k0 + scol, Bs + c * 512);
        }
        asm volatile("s_waitcnt vmcnt(0)" ::: "memory");
        __syncthreads();
        bf16x8 af[4], bfr[4];
#pragma unroll
        for (int i = 0; i < 4; ++i) af[i] = *(const bf16x8*)(As + (wr * 64 + i * 16 + lr) * 32 + quad * 8);
#pragma unroll
        for (int j = 0; j < 4; ++j) bfr[j] = *(const bf16x8*)(Bs + (wc * 64 + j * 16 + lr) * 32 + quad * 8);
#pragma unroll
        for (int i = 0; i < 4; ++i)
#pragma unroll
            for (int j = 0; j < 4; ++j)
                acc[i][j] = __builtin_amdgcn_mfma_f32_16x16x32_bf16(af[i], bfr[j], acc[i][j], 0, 0, 0);
    }

    size_t bm = m0 + wr * 64 + quad * 4;
    size_t bn = n0 + wc * 64 + lr;
#pragma unroll
    for (int i = 0; i < 4; ++i)
#pragma unroll
        for (int j = 0; j < 4; ++j)
#pragma unroll
            for (int r = 0; r < 4; ++r)
                C[(bm + i * 16 + r) * (size_t)N + bn + j * 16] = (CT)acc[i][j][r];
}

// ========== 256x128-tile GEMM for QKV (r7 schedule, FROZEN) =======================
#define QK_K 2048
#define QK_N 6144

__device__ __forceinline__ bf16x8 lds_frag(const bf16* tile, int row, int colByte) {
    int off = row * 128 + (colByte ^ ((row & 7) << 4));
    return *(const bf16x8*)((const char*)tile + off);
}

template <int MH>
__device__ __forceinline__ void mmaq16(f32x4 (&acc)[8][2], const bf16x8 (&afr)[4][2],
                                       const bf16x8 (&bf)[2][2]) {
    __builtin_amdgcn_s_setprio(1);
#pragma unroll
    for (int i = 0; i < 4; ++i)
#pragma unroll
        for (int j = 0; j < 2; ++j)
#pragma unroll
            for (int kk = 0; kk < 2; ++kk)
                acc[MH * 4 + i][j] = __builtin_amdgcn_mfma_f32_16x16x32_bf16(
                    afr[i][kk], bf[j][kk], acc[MH * 4 + i][j], 0, 0, 0);
    __builtin_amdgcn_s_setprio(0);
}

__global__ __launch_bounds__(512, 2) void gemm_qkv(const bf16* __restrict__ A,
                                                   const bf16* __restrict__ Bt,
                                                   bf16* __restrict__ C) {
    __shared__ __align__(16) bf16 As[3][256 * 64];  // 96 KB
    __shared__ __align__(16) bf16 Bs[3][128 * 64];  // 48 KB

    int t = threadIdx.x;
    int wid = t >> 6, lane = t & 63;
    int quad = lane >> 4, lr = lane & 15;
    int wr = wid >> 2, wn = wid & 3;  // 2 (M) x 4 (N) wave grid

    int bid = blockIdx.x;
    int swz = (bid & 7) * 96 + (bid >> 3);
    int tn = swz >> 4, tm = swz & 15;
    size_t m0 = (size_t)tm * 256, n0 = (size_t)tn * 128;

    int row_r[2], c8s_r[2];
#pragma unroll
    for (int r = 0; r < 2; ++r) {
        int idx = r * 512 + t;
        row_r[r] = idx >> 3;
        c8s_r[r] = (idx & 7) ^ (row_r[r] & 7);
    }

    auto stA = [&](int kt, int bufi, int h) {
#pragma unroll
        for (int r = 0; r < 2; ++r)
            async_load16(A + (m0 + h * 128 + row_r[r]) * (size_t)QK_K + kt * 64 + c8s_r[r] * 8,
                         &As[bufi][(h * 1024 + r * 512 + wid * 64) * 8]);
    };
    auto stB = [&](int kt, int bufi) {
#pragma unroll
        for (int r = 0; r < 2; ++r)
            async_load16(Bt + (n0 + row_r[r]) * (size_t)QK_K + kt * 64 + c8s_r[r] * 8,
                         &Bs[bufi][(r * 512 + wid * 64) * 8]);
    };

    f32x4 acc[8][2];
#pragma unroll
    for (int i = 0; i < 8; ++i)
#pragma unroll
        for (int j = 0; j < 2; ++j) acc[i][j] = (f32x4){0.f, 0.f, 0.f, 0.f};

    bf16x8 afr[4][2], bf[2][2];

    auto readA = [&](int bufi, int mh) {
#pragma unroll
        for (int i = 0; i < 4; ++i)
#pragma unroll
            for (int kk = 0; kk < 2; ++kk)
                afr[i][kk] = lds_frag(As[bufi], mh * 128 + wr * 64 + i * 16 + lr, kk * 64 + quad * 16);
    };
    auto readB = [&](int bufi) {
#pragma unroll
        for (int j = 0; j < 2; ++j)
#pragma unroll
            for (int kk = 0; kk < 2; ++kk)
                bf[j][kk] = lds_frag(Bs[bufi], wn * 32 + j * 16 + lr, kk * 64 + quad * 16);
    };

    stB(0, 0); stA(0, 0, 0); stA(0, 0, 1);
    stB(1, 1); stA(1, 1, 0); stA(1, 1, 1);
    asm volatile("s_waitcnt vmcnt(8)" ::: "memory");
    __builtin_amdgcn_s_barrier();

    auto tile2ph = [&](int kt, int cb, int nb2) {
        readA(cb, 0);
        readB(cb);
        stB(kt + 2, nb2);
        stA(kt + 2, nb2, 0);
        __builtin_amdgcn_s_barrier();
        asm volatile("s_waitcnt lgkmcnt(0)" ::: "memory");
        __builtin_amdgcn_sched_barrier(0);
        mmaq16<0>(acc, afr, bf);
        asm volatile("s_waitcnt vmcnt(10)" ::: "memory");
        __builtin_amdgcn_s_barrier();
        readA(cb, 1);
        stA(kt + 2, nb2, 1);
        __builtin_amdgcn_s_barrier();
        asm volatile("s_waitcnt lgkmcnt(0)" ::: "memory");
        __builtin_amdgcn_sched_barrier(0);
        mmaq16<1>(acc, afr, bf);
        asm volatile("s_waitcnt vmcnt(8)" ::: "memory");
        __builtin_amdgcn_s_barrier();
    };

    for (int kt3 = 0; kt3 < 30; kt3 += 3) {
        tile2ph(kt3 + 0, 0, 2);
        tile2ph(kt3 + 1, 1, 0);
        tile2ph(kt3 + 2, 2, 1);
    }

    {  // tail: tiles 30 (buf0) and 31 (buf1)
        readA(0, 0);
        readB(0);
        __builtin_amdgcn_s_barrier();
        asm volatile("s_waitcnt lgkmcnt(0)" ::: "memory");
        __builtin_amdgcn_sched_barrier(0);
        mmaq16<0>(acc, afr, bf);
        asm volatile("s_waitcnt vmcnt(6)" ::: "memory");
        __builtin_amdgcn_s_barrier();
        readA(0, 1);
        __builtin_amdgcn_s_barrier();
        asm volatile("s_waitcnt lgkmcnt(0)" ::: "memory");
        __builtin_amdgcn_sched_barrier(0);
        mmaq16<1>(acc, afr, bf);
        asm volatile("s_waitcnt vmcnt(2)" ::: "memory");
        __builtin_amdgcn_s_barrier();
        readA(1, 0);
        readB(1);
        __builtin_amdgcn_s_barrier();
        asm volatile("s_waitcnt lgkmcnt(0)" ::: "memory");
        __builtin_amdgcn_sched_barrier(0);
        mmaq16<0>(acc, afr, bf);
        asm volatile("s_waitcnt vmcnt(0)" ::: "memory");
        __builtin_amdgcn_s_barrier();
        readA(1, 1);
        asm volatile("s_waitcnt lgkmcnt(0)" ::: "memory");
        __builtin_amdgcn_sched_barrier(0);
        mmaq16<1>(acc, afr, bf);
    }

#pragma unroll
    for (int mh = 0; mh < 2; ++mh)
#pragma unroll
        for (int i = 0; i < 4; ++i)
#pragma unroll
            for (int j = 0; j < 2; ++j)
#pragma unroll
                for (int r = 0; r < 4; ++r) {
                    size_t row = m0 + mh * 128 + wr * 64 + i * 16 + quad * 4 + r;
                    size_t col = n0 + wn * 32 + j * 16 + lr;
                    C[row * QK_N + col] = (bf16)acc[mh * 4 + i][j][r];
                }
}

// ---------------- flash attention, causal (r6 4-wave + r8 XCD y-locality) ---------
// Round-8 change: XCD-aware block remap ONLY. Old mapping (x=p fastest) put the
// 16 p-sharers of each (b,h)'s K/V on ALL 8 XCDs and made every XCD stream all
// 32 y-values' K/V (32 MB) through its 4 MB L2 -> thrash -> HBM refetch.
// New: flat = y*16+p -> sid = (flat&7)*64 + (flat>>3) (bijective on [0,512));
// XCD x (= flat%8 round-robin) gets sid in [64x,64x+64) = y in [4x,4x+4):
// each XCD owns 4 y-values entirely (K/V footprint 4 MB ~= L2), all 16 sharers
// of a K/V co-located. Math/layout/staging untouched.
__global__ __launch_bounds__(256, 2) void attn_kernel(const bf16* __restrict__ qkv,
                                                      const bf16* __restrict__ vt,
                                                      bf16* __restrict__ ctx) {
    __shared__ __align__(16) bf16 Ks[2][64 * 128];    // [key][16B-chunk c ^ (key&7)]
    __shared__ __align__(16) bf16 Vts[2][128 * 64];   // [dh][16B-chunk c ^ (dh&7)]
    __shared__ __align__(16) bf16 Ps[4][16][68];      // per-wave P round-trip

    int flat = blockIdx.y * 16 + blockIdx.x;
    int sid = (flat & 7) * 64 + (flat >> 3);
    int y = sid >> 4;
    int p = sid & 15;
    int b = y >> 4, h = y & 15;
    int t = threadIdx.x, w = t >> 6, l = t & 63;
    int quad = l >> 4, lr = l & 15;

    const bf16* qbase = qkv + (size_t)b * S_ * QKVN + h * DH_;
    const bf16* kbase = qbase + D_;
    const bf16* vbase = vt + (size_t)y * DH_ * S_;

    const int qtA = p, qtB = 31 - p;
    const int nA = p + 1;  // iters for tile A; total 33

    auto stage = [&](int kt, int bi) {
#pragma unroll
        for (int ii = 0; ii < 4; ++ii) {
            int i = 4 * w + ii;
            int row = 4 * i + (l >> 4);
            int cl = (l & 15) ^ (row & 7);
            async_load16(kbase + (size_t)(kt * 64 + row) * QKVN + cl * 8, Ks[bi] + i * 512);
        }
#pragma unroll
        for (int ii = 0; ii < 4; ++ii) {
            int i = 4 * w + ii;
            int dh = 8 * i + (l >> 3);
            int cl = (l & 7) ^ (dh & 7);
            async_load16(vbase + (size_t)dh * S_ + kt * 64 + cl * 8, Vts[bi] + i * 512);
        }
    };

    const float sc2 = 0.12751745f;  // (1/sqrt(128)) * log2(e), folded into Q

    int qt = qtA, q0 = qt * 64;
    bf16x8 qf[4];
    auto loadQ = [&]() {
#pragma unroll
        for (int kk = 0; kk < 4; ++kk) {
            bf16x8 raw = *(const bf16x8*)(qbase + (size_t)(q0 + w * 16 + lr) * QKVN + kk * 32 + quad * 8);
#pragma unroll
            for (int e = 0; e < 8; ++e) qf[kk][e] = (bf16)((float)raw[e] * sc2);
        }
    };
    loadQ();

    float L_r[4];
    f32x4 o[8];
#pragma unroll
    for (int r = 0; r < 4; ++r) L_r[r] = 0.f;
#pragma unroll
    for (int nt = 0; nt < 8; ++nt) o[nt] = (f32x4){0.f, 0.f, 0.f, 0.f};

    auto epilogue = [&](int q0e) {
#pragma unroll
        for (int d = 1; d < 16; d <<= 1)
#pragma unroll
            for (int r = 0; r < 4; ++r) L_r[r] += __shfl_xor(L_r[r], d, 64);
#pragma unroll
        for (int r = 0; r < 4; ++r) {
            float inv = __builtin_amdgcn_rcpf(L_r[r]);
            int q = q0e + w * 16 + quad * 4 + r;
#pragma unroll
            for (int nt = 0; nt < 8; ++nt)
                ctx[(size_t)(b * S_ + q) * D_ + h * DH_ + nt * 16 + lr] = (bf16)(o[nt][r] * inv);
        }
    };

    stage(0, 0);  // prologue

    for (int it = 0; it < 33; ++it) {
        int buf = it & 1;
        asm volatile("s_waitcnt vmcnt(0)" ::: "memory");
        __syncthreads();
        if (it + 1 < 33) {
            int nit = it + 1;
            int nkt = (nit < nA) ? nit : (nit - nA);
            stage(nkt, buf ^ 1);  // in flight across this iter's compute
        }
        int kt = (it < nA) ? it : (it - nA);

        // S = Q K^T: 16 q-rows x 64 keys per wave
        f32x4 s[4];
#pragma unroll
        for (int jt = 0; jt < 4; ++jt) s[jt] = (f32x4){0.f, 0.f, 0.f, 0.f};
#pragma unroll
        for (int kk = 0; kk < 4; ++kk)
#pragma unroll
            for (int jt = 0; jt < 4; ++jt) {
                bf16x8 kf = *(const bf16x8*)(Ks[buf] + (jt * 16 + lr) * 128 + ((4 * kk + quad) ^ (lr & 7)) * 8);
                s[jt] = __builtin_amdgcn_mfma_f32_16x16x32_bf16(qf[kk], kf, s[jt], 0, 0, 0);
            }

        // exp2 (m=0) + mask (diag k-tile only) + per-lane L accumulation + P store
        bool diag = (kt == qt);
#pragma unroll
        for (int jt = 0; jt < 4; ++jt) {
            int keyi = jt * 16 + lr;
#pragma unroll
            for (int r = 0; r < 4; ++r) {
                float s2 = s[jt][r];
                if (diag && keyi > w * 16 + quad * 4 + r) s2 = -3.0e38f;
                float pv = __builtin_amdgcn_exp2f(s2);
                s[jt][r] = pv;
                L_r[r] += pv;
            }
        }
#pragma unroll
        for (int jt = 0; jt < 4; ++jt)
#pragma unroll
            for (int r = 0; r < 4; ++r)
                Ps[w][quad * 4 + r][jt * 16 + lr] = (bf16)s[jt][r];
        asm volatile("s_waitcnt lgkmcnt(0)" ::: "memory");  // per-wave Ps region

        // O += P @ V
#pragma unroll
        for (int ks = 0; ks < 2; ++ks) {
            const bf16* pp = &Ps[w][lr][ks * 32 + quad * 8];
            bf16x4 lo = *(const bf16x4*)pp;
            bf16x4 hi = *(const bf16x4*)(pp + 4);
            bf16x8 pf = __builtin_shufflevector(lo, hi, 0, 1, 2, 3, 4, 5, 6, 7);
#pragma unroll
            for (int nt = 0; nt < 8; ++nt) {
                bf16x8 vf = *(const bf16x8*)(Vts[buf] + (nt * 16 + lr) * 64 + ((4 * ks + quad) ^ (lr & 7)) * 8);
                o[nt] = __builtin_amdgcn_mfma_f32_16x16x32_bf16(pf, vf, o[nt], 0, 0, 0);
            }
        }

        // tile switch A -> B after A's diagonal iteration
        if (it == nA - 1) {
            epilogue(q0);
            qt = qtB;
            q0 = qt * 64;
            loadQ();
#pragma unroll
            for (int r = 0; r < 4; ++r) L_r[r] = 0.f;
#pragma unroll
            for (int nt = 0; nt < 8; ++nt) o[nt] = (f32x4){0.f, 0.f, 0.f, 0.f};
        }
    }

    epilogue(q0);  // tile B
}

extern "C" void kernel_launch(void* const* d_in, const int* in_sizes, int n_in,
                              void* d_out, int out_size, void* d_ws, size_t ws_size,
                              hipStream_t stream) {
    const float* x  = (const float*)d_in[0];
    const float* Wq = (const float*)d_in[1];
    const float* Wk = (const float*)d_in[2];
    const float* Wv = (const float*)d_in[3];
    const float* Wo = (const float*)d_in[4];
    float* out = (float*)d_out;

    char* ws = (char*)d_ws;
    bf16* WqkvT = (bf16*)(ws);                       // 3*2048*2048*2 = 25165824
    bf16* WoT   = (bf16*)(ws + 25165824);            // 2048*2048*2   =  8388608
    bf16* qkv   = (bf16*)(ws + 33554432);            // 4096*6144*2   = 50331648
    bf16* vt    = (bf16*)(ws + 83886080);            // 32*128*2048*2 = 16777216
    bf16* ctx   = (bf16*)(ws + 100663296);           // 4096*2048*2   = 16777216
    bf16* xb    = (bf16*)(ws + 117440512);           // 4096*2048*2   = 16777216
    // total ws use: 134217728 bytes (128 MiB)

    cvt_kernel<<<4096, 256, 0, stream>>>(x, xb);
    wtrans_kernel<<<dim3(32, 32, 4), 256, 0, stream>>>(Wq, Wk, Wv, Wo, WqkvT, WoT);
    gemm_qkv<<<dim3(768), 512, 0, stream>>>(xb, WqkvT, qkv);
    vtrans_kernel<<<dim3(32, 2, 32), 256, 0, stream>>>(qkv, vt);
    attn_kernel<<<dim3(16, 32), 256, 0, stream>>>(qkv, vt, ctx);
    gemm_bt<float><<<dim3(16, 32), 256, 0, stream>>>(ctx, WoT, out, B_ * S_, D_, D_);
}